// Round 2
// baseline (5003.346 us; speedup 1.0000x reference)
//
#include <hip/hip_runtime.h>
#include <hip/hip_bf16.h>
#include <math.h>

// ---------------------------------------------------------------------------
// KVPLM Star Encoder: 12 layers, H=768, NH=12, F=3072, B=16, S=512.
// Round 2: 256x256 8-phase GEMM (T1+T2+T3/T4+T5 per m201 template), fused QKV.
// ---------------------------------------------------------------------------

#define L_   12
#define H_   768
#define NH_  12
#define DH_  64
#define F_   3072
#define B_   16
#define S_   512
#define NTOK (B_ * S_)   // 8192
#define QKVN 2304

typedef __attribute__((ext_vector_type(8))) __bf16 bf16x8;
typedef __attribute__((ext_vector_type(4))) float  f32x4;

static __device__ __forceinline__ f32x4 mfma16(bf16x8 a, bf16x8 b, f32x4 c) {
  return __builtin_amdgcn_mfma_f32_16x16x32_bf16(a, b, c, 0, 0, 0);
}

static __device__ __forceinline__ void load_lds16(const void* g, void* l) {
  __builtin_amdgcn_global_load_lds(
      (const __attribute__((address_space(1))) void*)g,
      (__attribute__((address_space(3))) void*)l, 16, 0, 0);
}

// ---------------------------------------------------------------------------
// Weight transpose+convert: in fp32 [Z][R][C] -> out bf16 [Z (stride outZ)][C][R]
// ---------------------------------------------------------------------------
__global__ __launch_bounds__(256) void transpose_k(const float* __restrict__ in,
                                                   __bf16* __restrict__ out,
                                                   int R, int C, size_t outZ) {
  __shared__ float t[32][33];
  const int z = blockIdx.z;
  const float* inz = in + (size_t)z * R * C;
  __bf16* outz = out + (size_t)z * outZ;
  const int c0 = blockIdx.x * 32, r0 = blockIdx.y * 32;
  const int tx = threadIdx.x, ty = threadIdx.y;
#pragma unroll
  for (int i = 0; i < 32; i += 8)
    t[ty + i][tx] = inz[(size_t)(r0 + ty + i) * C + c0 + tx];
  __syncthreads();
#pragma unroll
  for (int i = 0; i < 32; i += 8)
    outz[(size_t)(c0 + ty + i) * R + r0 + tx] = (__bf16)t[tx][ty + i];
}

__global__ __launch_bounds__(256) void concat_bias(const float* __restrict__ bq,
                                                   const float* __restrict__ bk,
                                                   const float* __restrict__ bv,
                                                   float* __restrict__ o) {
  const int i = blockIdx.x * 256 + threadIdx.x;
  if (i >= L_ * QKVN) return;
  const int l = i / QKVN, j = i - l * QKVN;
  float v;
  if (j < H_) v = bq[l * H_ + j];
  else if (j < 2 * H_) v = bk[l * H_ + j - H_];
  else v = bv[l * H_ + j - 2 * H_];
  o[i] = v;
}

// ---------------------------------------------------------------------------
// 8-phase 256x256 GEMM (m201 template, plain HIP).
// C[M,N] = A[M,K](bf16) @ Bt[N,K]^T(bf16) + bias.  BK=64, 8 waves (2M x 4N),
// per-wave 128x64 output. LDS 128KiB: [buf2][A/B][half2][8192 el], where a
// half = 128 rows x 64 k-cols stored as [rg8][cg2][16][32] subtiles with
// element swizzle E ^= ((E>>8)&1)<<4 (st_16x32). global_load_lds writes
// linearly; the global SOURCE is inverse-swizzled (rule #21).
// Phase reads: q0: A0-3+B0-1 (12 ds_read_b128), q1: A4-7+B2-3 (12), q2/q3: 0.
// Stage slots: q0: A(t+1)h1 -> buf^1 | q2: B(t+2)h0,h1 -> buf | q3: A(t+2)h0.
// All of tile t+1 is issued by t.q0, so vmcnt(6) at t.q3 (newest 3 halves =
// tile t+2's) guarantees tile t+1 resident. Overwrite-safety: A/B regions of
// tile t are fully consumed by end of q1 (barriers), stages land q2+.
// ---------------------------------------------------------------------------
template <int EPI, int OUTBF>
__global__ __launch_bounds__(512, 2) void gemm8(const __bf16* __restrict__ A,
                                                const __bf16* __restrict__ Bt,
                                                const float* __restrict__ bias,
                                                float* __restrict__ Cf,
                                                __bf16* __restrict__ Cb,
                                                int M, int N, int K, int Ntiles) {
  alignas(16) __shared__ __bf16 lds[65536];  // 128 KiB
  const int tid = threadIdx.x, wid = tid >> 6, lane = tid & 63;
  int bid = blockIdx.x;
  const int nwg = gridDim.x;
  if ((nwg & 7) == 0) bid = (bid & 7) * (nwg >> 3) + (bid >> 3);  // XCD swizzle
  const int bm = (bid / Ntiles) << 8, bn = (bid % Ntiles) << 8;
  const int nt = K >> 6;

  // per-thread staging source coords (inverse-swizzled global address)
  const __bf16* pA[2];
  const __bf16* pB[2];
#pragma unroll
  for (int j = 0; j < 2; ++j) {
    const int E = (j << 12) + tid * 8;          // linear LDS element
    const int Ep = E ^ (((E >> 8) & 1) << 4);   // logical element
    const int r = ((Ep >> 10) << 4) | ((Ep >> 5) & 15);
    const int c = (((Ep >> 9) & 1) << 5) | (Ep & 31);
    pA[j] = A + (size_t)(bm + r) * K + c;
    pB[j] = Bt + (size_t)(bn + r) * K + c;
  }
  const size_t hstr = (size_t)128 * K;

  auto stage = [&](int ab, int h, int t, int buf) {
    __bf16* dst = &lds[((((buf << 1) + ab) << 1) + h) * 8192 + (wid << 9)];
    const size_t goff = (size_t)h * hstr + (size_t)(t << 6);
    load_lds16((ab ? pB[0] : pA[0]) + goff, dst);
    load_lds16((ab ? pB[1] : pA[1]) + goff, dst + 4096);
  };

  const int frow = lane & 15, fk = (lane >> 4) << 3;
  const int swzb = (frow * 32 + fk) ^ (((frow >> 3) & 1) << 4);
  const int mh = wid >> 2, nq = wid & 3;

  f32x4 acc[8][4] = {};

  // prologue: tile0 (4 halves), tile1 (Bh0,Bh1,Ah0)
  stage(0, 0, 0, 0); stage(0, 1, 0, 0); stage(1, 0, 0, 0); stage(1, 1, 0, 0);
  if (nt > 1) {
    asm volatile("s_waitcnt vmcnt(4)" ::: "memory");
    stage(1, 0, 1, 1); stage(1, 1, 1, 1); stage(0, 0, 1, 1);
  }
  asm volatile("s_waitcnt vmcnt(6)" ::: "memory");
  __builtin_amdgcn_s_barrier();

  for (int t = 0; t < nt; ++t) {
    const int buf = t & 1;
    const __bf16* LA = &lds[(((buf << 1) + 0) * 2 + mh) * 8192];
    const __bf16* LB = &lds[(((buf << 1) + 1) * 2 + (nq >> 1)) * 8192 + ((nq & 1) << 12)];
    bf16x8 a0[4][2], a1[4][2], b0[2][2], b1[2][2];

    // ---- phase 0: read A0-3, B0-1; stage A(t+1)h1; MFMA (m-lo, n-lo) ----
#pragma unroll
    for (int mi = 0; mi < 4; ++mi)
#pragma unroll
      for (int ks = 0; ks < 2; ++ks)
        a0[mi][ks] = *(const bf16x8*)&LA[mi * 1024 + ks * 512 + swzb];
#pragma unroll
    for (int ni = 0; ni < 2; ++ni)
#pragma unroll
      for (int ks = 0; ks < 2; ++ks)
        b0[ni][ks] = *(const bf16x8*)&LB[ni * 1024 + ks * 512 + swzb];
    if (t + 1 < nt) stage(0, 1, t + 1, buf ^ 1);
    __builtin_amdgcn_s_barrier();
    asm volatile("s_waitcnt lgkmcnt(0)" ::: "memory");
    __builtin_amdgcn_s_setprio(1);
#pragma unroll
    for (int mi = 0; mi < 4; ++mi)
#pragma unroll
      for (int ni = 0; ni < 2; ++ni)
#pragma unroll
        for (int ks = 0; ks < 2; ++ks)
          acc[mi][ni] = mfma16(a0[mi][ks], b0[ni][ks], acc[mi][ni]);
    __builtin_amdgcn_s_setprio(0);
    __builtin_amdgcn_s_barrier();

    // ---- phase 1: read A4-7, B2-3; MFMA (m-lo, n-hi) ----
#pragma unroll
    for (int mi = 0; mi < 4; ++mi)
#pragma unroll
      for (int ks = 0; ks < 2; ++ks)
        a1[mi][ks] = *(const bf16x8*)&LA[(4 + mi) * 1024 + ks * 512 + swzb];
#pragma unroll
    for (int ni = 0; ni < 2; ++ni)
#pragma unroll
      for (int ks = 0; ks < 2; ++ks)
        b1[ni][ks] = *(const bf16x8*)&LB[(2 + ni) * 1024 + ks * 512 + swzb];
    __builtin_amdgcn_s_barrier();
    asm volatile("s_waitcnt lgkmcnt(0)" ::: "memory");
    __builtin_amdgcn_s_setprio(1);
#pragma unroll
    for (int mi = 0; mi < 4; ++mi)
#pragma unroll
      for (int ni = 0; ni < 2; ++ni)
#pragma unroll
        for (int ks = 0; ks < 2; ++ks)
          acc[mi][2 + ni] = mfma16(a0[mi][ks], b1[ni][ks], acc[mi][2 + ni]);
    __builtin_amdgcn_s_setprio(0);
    __builtin_amdgcn_s_barrier();

    // ---- phase 2: stage B(t+2)h0,h1; MFMA (m-hi, n-hi) ----
    if (t + 2 < nt) { stage(1, 0, t + 2, buf); stage(1, 1, t + 2, buf); }
    __builtin_amdgcn_s_barrier();
    __builtin_amdgcn_s_setprio(1);
#pragma unroll
    for (int mi = 0; mi < 4; ++mi)
#pragma unroll
      for (int ni = 0; ni < 2; ++ni)
#pragma unroll
        for (int ks = 0; ks < 2; ++ks)
          acc[4 + mi][2 + ni] = mfma16(a1[mi][ks], b1[ni][ks], acc[4 + mi][2 + ni]);
    __builtin_amdgcn_s_setprio(0);
    __builtin_amdgcn_s_barrier();

    // ---- phase 3: stage A(t+2)h0; vmcnt(6); MFMA (m-hi, n-lo) ----
    if (t + 2 < nt) {
      stage(0, 0, t + 2, buf);
      asm volatile("s_waitcnt vmcnt(6)" ::: "memory");
    } else {
      asm volatile("s_waitcnt vmcnt(0)" ::: "memory");
    }
    __builtin_amdgcn_s_barrier();
    __builtin_amdgcn_s_setprio(1);
#pragma unroll
    for (int mi = 0; mi < 4; ++mi)
#pragma unroll
      for (int ni = 0; ni < 2; ++ni)
#pragma unroll
        for (int ks = 0; ks < 2; ++ks)
          acc[4 + mi][ni] = mfma16(a1[mi][ks], b0[ni][ks], acc[4 + mi][ni]);
    __builtin_amdgcn_s_setprio(0);
    __builtin_amdgcn_s_barrier();
  }

  // epilogue: C/D layout col=lane&15, row=(lane>>4)*4+r  [m89 verified]
  const int r0 = (lane >> 4) << 2, c0 = lane & 15;
  const int wrow = bm + (mh << 7), wcol = bn + (nq << 6);
#pragma unroll
  for (int ni = 0; ni < 4; ++ni) {
    const int col = wcol + (ni << 4) + c0;
    const float bv = bias[col];
#pragma unroll
    for (int f = 0; f < 8; ++f) {
      const int row = wrow + (f << 4) + r0;
#pragma unroll
      for (int r = 0; r < 4; ++r) {
        float v = acc[f][ni][r] + bv;
        if (EPI == 1) v = 0.5f * v * (1.0f + erff(v * 0.70710678118654752f));
        if (OUTBF)
          Cb[(size_t)(row + r) * N + col] = (__bf16)v;
        else
          Cf[(size_t)(row + r) * N + col] = v;
      }
    }
  }
}

// ---------------------------------------------------------------------------
// Flash attention over fused QKV buffer [NTOK][2304]: q at col h*64,
// k at 768+h*64, v at 1536+h*64. One block per (h,b); K/V staged in LDS.
// ---------------------------------------------------------------------------
__global__ __launch_bounds__(256) void attn_kernel(const __bf16* __restrict__ qkv,
                                                   const int* __restrict__ amask,
                                                   __bf16* __restrict__ ctx) {
  __shared__ __bf16 Kl[S_][72];        // [key][d]  (pad 64->72)
  __shared__ __bf16 Vt[DH_][S_ + 8];   // [d][key]  (pad 512->520)
  __shared__ float extm[S_];
  __shared__ __bf16 Pl[4][16][56];     // per-wave P tile (pad 32->56)
  const int h = blockIdx.x, b = blockIdx.y;
  const int tid = threadIdx.x, wid = tid >> 6, lane = tid & 63;
  const size_t rowb = (size_t)b * S_ * QKVN + (size_t)h * DH_;

  for (int c = tid; c < S_ * DH_ / 8; c += 256) {
    const int s = c >> 3, d8 = (c & 7) << 3;
    bf16x8 kv = *(const bf16x8*)(qkv + rowb + (size_t)s * QKVN + H_ + d8);
    *(bf16x8*)&Kl[s][d8] = kv;
    bf16x8 vv = *(const bf16x8*)(qkv + rowb + (size_t)s * QKVN + 2 * H_ + d8);
#pragma unroll
    for (int j = 0; j < 8; ++j) Vt[d8 + j][s] = vv[j];
  }
  for (int i = tid; i < S_; i += 256)
    extm[i] = (1.0f - (float)amask[b * S_ + i]) * -10000.0f;
  __syncthreads();

  const int c0 = lane & 15, g4 = lane >> 4;
  for (int qt = wid; qt < S_ / 16; qt += 4) {
    const __bf16* qrow = qkv + rowb + (size_t)(qt * 16 + c0) * QKVN + (g4 << 3);
    const bf16x8 qf0 = *(const bf16x8*)qrow;
    const bf16x8 qf1 = *(const bf16x8*)(qrow + 32);
    f32x4 oacc[4] = {};
    float mrow[4] = {-1e30f, -1e30f, -1e30f, -1e30f};
    float lsum[4] = {0.f, 0.f, 0.f, 0.f};

    for (int kt = 0; kt < 16; ++kt) {
      f32x4 sc[2];
#pragma unroll
      for (int f = 0; f < 2; ++f) {
        const int key = kt * 32 + f * 16 + c0;
        const bf16x8 kf0 = *(const bf16x8*)&Kl[key][g4 << 3];
        const bf16x8 kf1 = *(const bf16x8*)&Kl[key][32 + (g4 << 3)];
        f32x4 z = {};
        z = mfma16(qf0, kf0, z);
        z = mfma16(qf1, kf1, z);
        const float e = extm[key];
#pragma unroll
        for (int r = 0; r < 4; ++r) sc[f][r] = z[r] * 0.125f + e;
      }
      float al[4];
#pragma unroll
      for (int r = 0; r < 4; ++r) {
        float mx = fmaxf(sc[0][r], sc[1][r]);
        mx = fmaxf(mx, __shfl_xor(mx, 1, 64));
        mx = fmaxf(mx, __shfl_xor(mx, 2, 64));
        mx = fmaxf(mx, __shfl_xor(mx, 4, 64));
        mx = fmaxf(mx, __shfl_xor(mx, 8, 64));
        const float mn = fmaxf(mrow[r], mx);
        al[r] = __expf(mrow[r] - mn);
        mrow[r] = mn;
        const float p0 = __expf(sc[0][r] - mn);
        const float p1 = __expf(sc[1][r] - mn);
        sc[0][r] = p0; sc[1][r] = p1;
        float rs = p0 + p1;
        rs += __shfl_xor(rs, 1, 64);
        rs += __shfl_xor(rs, 2, 64);
        rs += __shfl_xor(rs, 4, 64);
        rs += __shfl_xor(rs, 8, 64);
        lsum[r] = lsum[r] * al[r] + rs;
      }
#pragma unroll
      for (int f = 0; f < 2; ++f)
#pragma unroll
        for (int r = 0; r < 4; ++r)
          Pl[wid][g4 * 4 + r][f * 16 + c0] = (__bf16)sc[f][r];
#pragma unroll
      for (int dt = 0; dt < 4; ++dt)
#pragma unroll
        for (int r = 0; r < 4; ++r) oacc[dt][r] *= al[r];
      const bf16x8 pa = *(const bf16x8*)&Pl[wid][c0][g4 << 3];
#pragma unroll
      for (int dt = 0; dt < 4; ++dt) {
        const bf16x8 vf =
            *(const bf16x8*)&Vt[dt * 16 + c0][kt * 32 + (g4 << 3)];
        oacc[dt] = mfma16(pa, vf, oacc[dt]);
      }
    }
    float inv[4];
#pragma unroll
    for (int r = 0; r < 4; ++r) inv[r] = 1.0f / lsum[r];
#pragma unroll
    for (int dt = 0; dt < 4; ++dt)
#pragma unroll
      for (int r = 0; r < 4; ++r)
        ctx[(size_t)b * S_ * H_ + (size_t)h * DH_ +
            (size_t)(qt * 16 + g4 * 4 + r) * H_ + dt * 16 + c0] =
            (__bf16)(oacc[dt][r] * inv[r]);
  }
}

// ---------------------------------------------------------------------------
// Residual add + LayerNorm (fp32 stream) + bf16 mirror.
// ---------------------------------------------------------------------------
__global__ __launch_bounds__(256) void addln_kernel(float* __restrict__ x,
                                                    const float* __restrict__ t,
                                                    const float* __restrict__ g,
                                                    const float* __restrict__ bb,
                                                    __bf16* __restrict__ xb) {
  const int tok = blockIdx.x, tid = threadIdx.x;
  float* xr = x + (size_t)tok * H_;
  const float* tr = t + (size_t)tok * H_;
  float v0 = xr[tid] + tr[tid];
  float v1 = xr[tid + 256] + tr[tid + 256];
  float v2 = xr[tid + 512] + tr[tid + 512];
  float s = v0 + v1 + v2;
  float s2 = v0 * v0 + v1 * v1 + v2 * v2;
  __shared__ float red1[4], red2[4];
#pragma unroll
  for (int o = 32; o > 0; o >>= 1) {
    s += __shfl_xor(s, o, 64);
    s2 += __shfl_xor(s2, o, 64);
  }
  if ((tid & 63) == 0) { red1[tid >> 6] = s; red2[tid >> 6] = s2; }
  __syncthreads();
  s = red1[0] + red1[1] + red1[2] + red1[3];
  s2 = red2[0] + red2[1] + red2[2] + red2[3];
  const float mean = s * (1.0f / 768.0f);
  const float var = s2 * (1.0f / 768.0f) - mean * mean;
  const float rstd = rsqrtf(var + 1e-12f);
  const float y0 = (v0 - mean) * rstd * g[tid] + bb[tid];
  const float y1 = (v1 - mean) * rstd * g[tid + 256] + bb[tid + 256];
  const float y2 = (v2 - mean) * rstd * g[tid + 512] + bb[tid + 512];
  xr[tid] = y0; xr[tid + 256] = y1; xr[tid + 512] = y2;
  __bf16* xbr = xb + (size_t)tok * H_;
  xbr[tid] = (__bf16)y0; xbr[tid + 256] = (__bf16)y1; xbr[tid + 512] = (__bf16)y2;
}

// ---------------------------------------------------------------------------
// Embedding (word/star select + pos + type) + LN.
// ---------------------------------------------------------------------------
__global__ __launch_bounds__(256) void embed_kernel(
    const int* __restrict__ ids, const int* __restrict__ tt,
    const float* __restrict__ we, const float* __restrict__ se,
    const float* __restrict__ pe, const float* __restrict__ te,
    const float* __restrict__ g, const float* __restrict__ bb,
    float* __restrict__ x, __bf16* __restrict__ xb) {
  const int tok = blockIdx.x, tid = threadIdx.x;
  const int sp = tok & (S_ - 1);
  const int id = ids[tok];
  const float* e = (id >= 30700) ? se + (size_t)(id - 30700) * H_
                                 : we + (size_t)id * H_;
  const float* pr = pe + (size_t)sp * H_;
  const float* ty = te + (size_t)tt[tok] * H_;
  float v0 = e[tid] + pr[tid] + ty[tid];
  float v1 = e[tid + 256] + pr[tid + 256] + ty[tid + 256];
  float v2 = e[tid + 512] + pr[tid + 512] + ty[tid + 512];
  float s = v0 + v1 + v2;
  float s2 = v0 * v0 + v1 * v1 + v2 * v2;
  __shared__ float red1[4], red2[4];
#pragma unroll
  for (int o = 32; o > 0; o >>= 1) {
    s += __shfl_xor(s, o, 64);
    s2 += __shfl_xor(s2, o, 64);
  }
  if ((tid & 63) == 0) { red1[tid >> 6] = s; red2[tid >> 6] = s2; }
  __syncthreads();
  s = red1[0] + red1[1] + red1[2] + red1[3];
  s2 = red2[0] + red2[1] + red2[2] + red2[3];
  const float mean = s * (1.0f / 768.0f);
  const float var = s2 * (1.0f / 768.0f) - mean * mean;
  const float rstd = rsqrtf(var + 1e-12f);
  float* xr = x + (size_t)tok * H_;
  __bf16* xbr = xb + (size_t)tok * H_;
  const float y0 = (v0 - mean) * rstd * g[tid] + bb[tid];
  const float y1 = (v1 - mean) * rstd * g[tid + 256] + bb[tid + 256];
  const float y2 = (v2 - mean) * rstd * g[tid + 512] + bb[tid + 512];
  xr[tid] = y0; xr[tid + 256] = y1; xr[tid + 512] = y2;
  xbr[tid] = (__bf16)y0; xbr[tid + 256] = (__bf16)y1; xbr[tid + 512] = (__bf16)y2;
}

// ---------------------------------------------------------------------------
// Pooler: pooled[b] = tanh(x[b,0,:] @ poolW + pool_b).
// ---------------------------------------------------------------------------
__global__ __launch_bounds__(256) void pool_kernel(const float* __restrict__ x,
                                                   const __bf16* __restrict__ wT,
                                                   const float* __restrict__ pb,
                                                   float* __restrict__ out) {
  const int b = blockIdx.x, tid = threadIdx.x;
  __shared__ float xr[H_];
  for (int i = tid; i < H_; i += 256) xr[i] = x[(size_t)b * S_ * H_ + i];
  __syncthreads();
  for (int n = tid; n < H_; n += 256) {
    const __bf16* w = wT + (size_t)n * H_;
    float acc = 0.f;
    for (int k = 0; k < H_; ++k) acc += xr[k] * (float)w[k];
    out[(size_t)b * H_ + n] = tanhf(acc + pb[n]);
  }
}

// ---------------------------------------------------------------------------
extern "C" void kernel_launch(void* const* d_in, const int* in_sizes, int n_in,
                              void* d_out, int out_size, void* d_ws,
                              size_t ws_size, hipStream_t stream) {
  (void)in_sizes; (void)n_in; (void)out_size;
  const int* ids = (const int*)d_in[0];
  const int* am = (const int*)d_in[1];
  const int* tt = (const int*)d_in[2];
  const float* we = (const float*)d_in[3];
  const float* se = (const float*)d_in[4];
  const float* pe = (const float*)d_in[5];
  const float* te = (const float*)d_in[6];
  const float* eg = (const float*)d_in[7];
  const float* ebb = (const float*)d_in[8];
  const float* Wq = (const float*)d_in[9];
  const float* bq = (const float*)d_in[10];
  const float* Wk = (const float*)d_in[11];
  const float* bk = (const float*)d_in[12];
  const float* Wv = (const float*)d_in[13];
  const float* bv = (const float*)d_in[14];
  const float* Wo = (const float*)d_in[15];
  const float* bo = (const float*)d_in[16];
  const float* g1 = (const float*)d_in[17];
  const float* b1 = (const float*)d_in[18];
  const float* Wi = (const float*)d_in[19];
  const float* bi = (const float*)d_in[20];
  const float* Wf = (const float*)d_in[21];
  const float* bf_ = (const float*)d_in[22];
  const float* g2 = (const float*)d_in[23];
  const float* b2 = (const float*)d_in[24];
  const float* pw = (const float*)d_in[25];
  const float* pb = (const float*)d_in[26];

  const size_t WQKV = (size_t)L_ * QKVN * H_;
  const size_t WSQ = (size_t)L_ * H_ * H_;
  const size_t WSF = (size_t)L_ * H_ * F_;
  __bf16* wqkv = (__bf16*)d_ws;
  __bf16* wTo_ = wqkv + WQKV;
  __bf16* wTi_ = wTo_ + WSQ;
  __bf16* wTf_ = wTi_ + WSF;
  __bf16* wTp_ = wTf_ + WSF;
  __bf16* xb = wTp_ + (size_t)H_ * H_;
  __bf16* qkvb = xb + (size_t)NTOK * H_;
  __bf16* cb = qkvb + (size_t)NTOK * QKVN;
  __bf16* mid = cb + (size_t)NTOK * H_;
  float* t0 = (float*)(mid + (size_t)NTOK * F_);
  float* bqkv = t0 + (size_t)NTOK * H_;
  const size_t needed = (size_t)((char*)(bqkv + (size_t)L_ * QKVN) - (char*)d_ws);
  if (ws_size < needed) return;  // insufficient scratch: visible failure

  float* x = (float*)d_out;
  float* pooled = x + (size_t)NTOK * H_;

  const dim3 tb(32, 8);
  const size_t zq = (size_t)QKVN * H_;
  transpose_k<<<dim3(24, 24, 12), tb, 0, stream>>>(Wq, wqkv, H_, H_, zq);
  transpose_k<<<dim3(24, 24, 12), tb, 0, stream>>>(Wk, wqkv + (size_t)H_ * H_, H_, H_, zq);
  transpose_k<<<dim3(24, 24, 12), tb, 0, stream>>>(Wv, wqkv + 2 * (size_t)H_ * H_, H_, H_, zq);
  transpose_k<<<dim3(24, 24, 12), tb, 0, stream>>>(Wo, wTo_, H_, H_, (size_t)H_ * H_);
  transpose_k<<<dim3(96, 24, 12), tb, 0, stream>>>(Wi, wTi_, H_, F_, (size_t)H_ * F_);
  transpose_k<<<dim3(24, 96, 12), tb, 0, stream>>>(Wf, wTf_, F_, H_, (size_t)H_ * F_);
  transpose_k<<<dim3(24, 24, 1), tb, 0, stream>>>(pw, wTp_, H_, H_, (size_t)H_ * H_);
  concat_bias<<<(L_ * QKVN + 255) / 256, 256, 0, stream>>>(bq, bk, bv, bqkv);

  embed_kernel<<<NTOK, 256, 0, stream>>>(ids, tt, we, se, pe, te, eg, ebb, x, xb);

  for (int l = 0; l < L_; ++l) {
    // fused QKV: [8192,2304] = xb @ wqkv_l^T
    gemm8<0, 1><<<(NTOK / 256) * (QKVN / 256), 512, 0, stream>>>(
        xb, wqkv + (size_t)l * QKVN * H_, bqkv + (size_t)l * QKVN,
        nullptr, qkvb, NTOK, QKVN, H_, QKVN / 256);

    attn_kernel<<<dim3(NH_, B_), 256, 0, stream>>>(qkvb, am, cb);

    gemm8<0, 0><<<(NTOK / 256) * (H_ / 256), 512, 0, stream>>>(
        cb, wTo_ + (size_t)l * H_ * H_, bo + l * H_, t0, nullptr,
        NTOK, H_, H_, H_ / 256);
    addln_kernel<<<NTOK, 256, 0, stream>>>(x, t0, g1 + l * H_, b1 + l * H_, xb);

    gemm8<1, 1><<<(NTOK / 256) * (F_ / 256), 512, 0, stream>>>(
        xb, wTi_ + (size_t)l * H_ * F_, bi + l * F_, nullptr, mid,
        NTOK, F_, H_, F_ / 256);
    gemm8<0, 0><<<(NTOK / 256) * (H_ / 256), 512, 0, stream>>>(
        mid, wTf_ + (size_t)l * F_ * H_, bf_ + l * H_, t0, nullptr,
        NTOK, H_, F_, H_ / 256);
    addln_kernel<<<NTOK, 256, 0, stream>>>(x, t0, g2 + l * H_, b2 + l * H_, xb);
  }

  pool_kernel<<<B_, 256, 0, stream>>>(x, wTp_, pb, pooled);
}

// Round 3
// 4456.537 us; speedup vs baseline: 1.1227x; 1.1227x over previous
//
#include <hip/hip_runtime.h>
#include <hip/hip_bf16.h>
#include <math.h>

// ---------------------------------------------------------------------------
// KVPLM Star Encoder: 12 layers, H=768, NH=12, F=3072, B=16, S=512.
// Round 3: fix GEMM chip-fill. BM=256 4-phase kernel for FF1 (384 blocks);
// new BM=128 2-phase kernel (same T2 swizzle + counted vmcnt) for
// QKV (576 blocks) / AO (192) / FF2 (192). Wave-per-token addLN.
// ---------------------------------------------------------------------------

#define L_   12
#define H_   768
#define NH_  12
#define DH_  64
#define F_   3072
#define B_   16
#define S_   512
#define NTOK (B_ * S_)   // 8192
#define QKVN 2304

typedef __attribute__((ext_vector_type(8))) __bf16 bf16x8;
typedef __attribute__((ext_vector_type(4))) __bf16 bf16x4;
typedef __attribute__((ext_vector_type(4))) float  f32x4;

static __device__ __forceinline__ f32x4 mfma16(bf16x8 a, bf16x8 b, f32x4 c) {
  return __builtin_amdgcn_mfma_f32_16x16x32_bf16(a, b, c, 0, 0, 0);
}

static __device__ __forceinline__ void load_lds16(const void* g, void* l) {
  __builtin_amdgcn_global_load_lds(
      (const __attribute__((address_space(1))) void*)g,
      (__attribute__((address_space(3))) void*)l, 16, 0, 0);
}

// ---------------------------------------------------------------------------
// Weight transpose+convert: in fp32 [Z][R][C] -> out bf16 [Z (stride outZ)][C][R]
// ---------------------------------------------------------------------------
__global__ __launch_bounds__(256) void transpose_k(const float* __restrict__ in,
                                                   __bf16* __restrict__ out,
                                                   int R, int C, size_t outZ) {
  __shared__ float t[32][33];
  const int z = blockIdx.z;
  const float* inz = in + (size_t)z * R * C;
  __bf16* outz = out + (size_t)z * outZ;
  const int c0 = blockIdx.x * 32, r0 = blockIdx.y * 32;
  const int tx = threadIdx.x, ty = threadIdx.y;
#pragma unroll
  for (int i = 0; i < 32; i += 8)
    t[ty + i][tx] = inz[(size_t)(r0 + ty + i) * C + c0 + tx];
  __syncthreads();
#pragma unroll
  for (int i = 0; i < 32; i += 8)
    outz[(size_t)(c0 + ty + i) * R + r0 + tx] = (__bf16)t[tx][ty + i];
}

__global__ __launch_bounds__(256) void concat_bias(const float* __restrict__ bq,
                                                   const float* __restrict__ bk,
                                                   const float* __restrict__ bv,
                                                   float* __restrict__ o) {
  const int i = blockIdx.x * 256 + threadIdx.x;
  if (i >= L_ * QKVN) return;
  const int l = i / QKVN, j = i - l * QKVN;
  float v;
  if (j < H_) v = bq[l * H_ + j];
  else if (j < 2 * H_) v = bk[l * H_ + j - H_];
  else v = bv[l * H_ + j - 2 * H_];
  o[i] = v;
}

// ---------------------------------------------------------------------------
// 4-phase 256x256 GEMM (m201 template). Used for FF1 (grid 384).
// ---------------------------------------------------------------------------
template <int EPI, int OUTBF>
__global__ __launch_bounds__(512, 2) void gemm8(const __bf16* __restrict__ A,
                                                const __bf16* __restrict__ Bt,
                                                const float* __restrict__ bias,
                                                float* __restrict__ Cf,
                                                __bf16* __restrict__ Cb,
                                                int M, int N, int K, int Ntiles) {
  alignas(16) __shared__ __bf16 lds[65536];  // 128 KiB
  const int tid = threadIdx.x, wid = tid >> 6, lane = tid & 63;
  int bid = blockIdx.x;
  const int nwg = gridDim.x;
  if ((nwg & 7) == 0) bid = (bid & 7) * (nwg >> 3) + (bid >> 3);  // XCD swizzle
  const int bm = (bid / Ntiles) << 8, bn = (bid % Ntiles) << 8;
  const int nt = K >> 6;

  // per-thread staging source coords (inverse-swizzled global address, rule #21)
  const __bf16* pA[2];
  const __bf16* pB[2];
#pragma unroll
  for (int j = 0; j < 2; ++j) {
    const int E = (j << 12) + tid * 8;          // linear LDS element
    const int Ep = E ^ (((E >> 8) & 1) << 4);   // logical element (st_16x32)
    const int r = ((Ep >> 10) << 4) | ((Ep >> 5) & 15);
    const int c = (((Ep >> 9) & 1) << 5) | (Ep & 31);
    pA[j] = A + (size_t)(bm + r) * K + c;
    pB[j] = Bt + (size_t)(bn + r) * K + c;
  }
  const size_t hstr = (size_t)128 * K;

  auto stage = [&](int ab, int h, int t, int buf) {
    __bf16* dst = &lds[((((buf << 1) + ab) << 1) + h) * 8192 + (wid << 9)];
    const size_t goff = (size_t)h * hstr + (size_t)(t << 6);
    load_lds16((ab ? pB[0] : pA[0]) + goff, dst);
    load_lds16((ab ? pB[1] : pA[1]) + goff, dst + 4096);
  };

  const int frow = lane & 15, fk = (lane >> 4) << 3;
  const int swzb = (frow * 32 + fk) ^ (((frow >> 3) & 1) << 4);
  const int mh = wid >> 2, nq = wid & 3;

  f32x4 acc[8][4] = {};

  // prologue: tile0 (4 halves), tile1 (Bh0,Bh1,Ah0)
  stage(0, 0, 0, 0); stage(0, 1, 0, 0); stage(1, 0, 0, 0); stage(1, 1, 0, 0);
  if (nt > 1) {
    asm volatile("s_waitcnt vmcnt(4)" ::: "memory");
    stage(1, 0, 1, 1); stage(1, 1, 1, 1); stage(0, 0, 1, 1);
  }
  asm volatile("s_waitcnt vmcnt(6)" ::: "memory");
  __builtin_amdgcn_s_barrier();

  for (int t = 0; t < nt; ++t) {
    const int buf = t & 1;
    const __bf16* LA = &lds[(((buf << 1) + 0) * 2 + mh) * 8192];
    const __bf16* LB = &lds[(((buf << 1) + 1) * 2 + (nq >> 1)) * 8192 + ((nq & 1) << 12)];
    bf16x8 a0[4][2], a1[4][2], b0[2][2], b1[2][2];

    // ---- q0: read A0-3,B0-1; stage A(t+1)h1 -> buf^1; MFMA (m-lo,n-lo) ----
#pragma unroll
    for (int mi = 0; mi < 4; ++mi)
#pragma unroll
      for (int ks = 0; ks < 2; ++ks)
        a0[mi][ks] = *(const bf16x8*)&LA[mi * 1024 + ks * 512 + swzb];
#pragma unroll
    for (int ni = 0; ni < 2; ++ni)
#pragma unroll
      for (int ks = 0; ks < 2; ++ks)
        b0[ni][ks] = *(const bf16x8*)&LB[ni * 1024 + ks * 512 + swzb];
    if (t + 1 < nt) stage(0, 1, t + 1, buf ^ 1);
    __builtin_amdgcn_s_barrier();
    asm volatile("s_waitcnt lgkmcnt(0)" ::: "memory");
    __builtin_amdgcn_s_setprio(1);
#pragma unroll
    for (int mi = 0; mi < 4; ++mi)
#pragma unroll
      for (int ni = 0; ni < 2; ++ni)
#pragma unroll
        for (int ks = 0; ks < 2; ++ks)
          acc[mi][ni] = mfma16(a0[mi][ks], b0[ni][ks], acc[mi][ni]);
    __builtin_amdgcn_s_setprio(0);
    __builtin_amdgcn_s_barrier();

    // ---- q1: read A4-7,B2-3; MFMA (m-lo,n-hi) ----
#pragma unroll
    for (int mi = 0; mi < 4; ++mi)
#pragma unroll
      for (int ks = 0; ks < 2; ++ks)
        a1[mi][ks] = *(const bf16x8*)&LA[(4 + mi) * 1024 + ks * 512 + swzb];
#pragma unroll
    for (int ni = 0; ni < 2; ++ni)
#pragma unroll
      for (int ks = 0; ks < 2; ++ks)
        b1[ni][ks] = *(const bf16x8*)&LB[(2 + ni) * 1024 + ks * 512 + swzb];
    __builtin_amdgcn_s_barrier();
    asm volatile("s_waitcnt lgkmcnt(0)" ::: "memory");
    __builtin_amdgcn_s_setprio(1);
#pragma unroll
    for (int mi = 0; mi < 4; ++mi)
#pragma unroll
      for (int ni = 0; ni < 2; ++ni)
#pragma unroll
        for (int ks = 0; ks < 2; ++ks)
          acc[mi][2 + ni] = mfma16(a0[mi][ks], b1[ni][ks], acc[mi][2 + ni]);
    __builtin_amdgcn_s_setprio(0);
    __builtin_amdgcn_s_barrier();

    // ---- q2: stage B(t+2) -> buf; MFMA (m-hi,n-hi) ----
    if (t + 2 < nt) { stage(1, 0, t + 2, buf); stage(1, 1, t + 2, buf); }
    __builtin_amdgcn_s_barrier();
    __builtin_amdgcn_s_setprio(1);
#pragma unroll
    for (int mi = 0; mi < 4; ++mi)
#pragma unroll
      for (int ni = 0; ni < 2; ++ni)
#pragma unroll
        for (int ks = 0; ks < 2; ++ks)
          acc[4 + mi][2 + ni] = mfma16(a1[mi][ks], b1[ni][ks], acc[4 + mi][2 + ni]);
    __builtin_amdgcn_s_setprio(0);
    __builtin_amdgcn_s_barrier();

    // ---- q3: stage A(t+2)h0 -> buf; vmcnt(6); MFMA (m-hi,n-lo) ----
    if (t + 2 < nt) {
      stage(0, 0, t + 2, buf);
      asm volatile("s_waitcnt vmcnt(6)" ::: "memory");
    } else {
      asm volatile("s_waitcnt vmcnt(0)" ::: "memory");
    }
    __builtin_amdgcn_s_barrier();
    __builtin_amdgcn_s_setprio(1);
#pragma unroll
    for (int mi = 0; mi < 4; ++mi)
#pragma unroll
      for (int ni = 0; ni < 2; ++ni)
#pragma unroll
        for (int ks = 0; ks < 2; ++ks)
          acc[4 + mi][ni] = mfma16(a1[mi][ks], b0[ni][ks], acc[4 + mi][ni]);
    __builtin_amdgcn_s_setprio(0);
    __builtin_amdgcn_s_barrier();
  }

  const int r0 = (lane >> 4) << 2, c0 = lane & 15;
  const int wrow = bm + (mh << 7), wcol = bn + (nq << 6);
#pragma unroll
  for (int ni = 0; ni < 4; ++ni) {
    const int col = wcol + (ni << 4) + c0;
    const float bv = bias[col];
#pragma unroll
    for (int f = 0; f < 8; ++f) {
      const int row = wrow + (f << 4) + r0;
#pragma unroll
      for (int r = 0; r < 4; ++r) {
        float v = acc[f][ni][r] + bv;
        if (EPI == 1) v = 0.5f * v * (1.0f + erff(v * 0.70710678118654752f));
        if (OUTBF)
          Cb[(size_t)(row + r) * N + col] = (__bf16)v;
        else
          Cf[(size_t)(row + r) * N + col] = v;
      }
    }
  }
}

// ---------------------------------------------------------------------------
// 2-phase 128x256 GEMM for narrow-N shapes (QKV/AO/FF2): better chip fill.
// LDS 96 KiB: A 2x8192 el, B 2x16384 el, same st_16x32 swizzle.
// Staging: t.p0 -> B(t+1) (buf^1, free since (t-1).p1); t.p1 -> A(t+2) (buf,
// free after t.p0). vmcnt(2) at p1 (counted, never 0 mid-loop) guarantees
// tile t+1 fully resident. Prologue: A0,B0h0,B0h1,A1; vmcnt(2).
// ---------------------------------------------------------------------------
template <int EPI, int OUTBF>
__global__ __launch_bounds__(512, 2) void gemm8n(const __bf16* __restrict__ A,
                                                 const __bf16* __restrict__ Bt,
                                                 const float* __restrict__ bias,
                                                 float* __restrict__ Cf,
                                                 __bf16* __restrict__ Cb,
                                                 int M, int N, int K, int Ntiles) {
  alignas(16) __shared__ __bf16 lds[49152];  // 96 KiB
  const int tid = threadIdx.x, wid = tid >> 6, lane = tid & 63;
  int bid = blockIdx.x;
  const int nwg = gridDim.x;
  if ((nwg & 7) == 0) bid = (bid & 7) * (nwg >> 3) + (bid >> 3);  // XCD swizzle
  const int bm = (bid / Ntiles) << 7, bn = (bid % Ntiles) << 8;
  const int nt = K >> 6;

  const __bf16* pA[2];
  const __bf16* pB[2];
#pragma unroll
  for (int j = 0; j < 2; ++j) {
    const int E = (j << 12) + tid * 8;
    const int Ep = E ^ (((E >> 8) & 1) << 4);
    const int r = ((Ep >> 10) << 4) | ((Ep >> 5) & 15);
    const int c = (((Ep >> 9) & 1) << 5) | (Ep & 31);
    pA[j] = A + (size_t)(bm + r) * K + c;
    pB[j] = Bt + (size_t)(bn + r) * K + c;
  }
  const size_t hstr = (size_t)128 * K;

  auto stageA = [&](int t, int buf) {
    __bf16* dst = &lds[buf * 8192 + (wid << 9)];
    load_lds16(pA[0] + (size_t)(t << 6), dst);
    load_lds16(pA[1] + (size_t)(t << 6), dst + 4096);
  };
  auto stageB = [&](int h, int t, int buf) {
    __bf16* dst = &lds[16384 + buf * 16384 + h * 8192 + (wid << 9)];
    const size_t goff = (size_t)h * hstr + (size_t)(t << 6);
    load_lds16(pB[0] + goff, dst);
    load_lds16(pB[1] + goff, dst + 4096);
  };

  const int frow = lane & 15, fk = (lane >> 4) << 3;
  const int swzb = (frow * 32 + fk) ^ (((frow >> 3) & 1) << 4);
  const int mh = wid >> 2, nq = wid & 3;  // 2 M-waves x 4 N-waves, 64x64 each

  f32x4 acc[4][4] = {};

  // prologue (order matters for vmcnt(2)): A0, B0h0, B0h1, A1
  stageA(0, 0); stageB(0, 0, 0); stageB(1, 0, 0);
  if (nt > 1) stageA(1, 1);
  asm volatile("s_waitcnt vmcnt(2)" ::: "memory");
  __builtin_amdgcn_s_barrier();

  for (int t = 0; t < nt; ++t) {
    const int buf = t & 1;
    const __bf16* LA = &lds[buf * 8192 + mh * 4096];
    const __bf16* LB = &lds[16384 + buf * 16384 + (nq >> 1) * 8192 + ((nq & 1) << 12)];
    bf16x8 a[4][2], blo[2][2], bhi[2][2];

    // ---- p0: read A(8) + B-lo(4); stage B(t+1) -> buf^1; MFMA n-lo ----
#pragma unroll
    for (int mi = 0; mi < 4; ++mi)
#pragma unroll
      for (int ks = 0; ks < 2; ++ks)
        a[mi][ks] = *(const bf16x8*)&LA[mi * 1024 + ks * 512 + swzb];
#pragma unroll
    for (int ni = 0; ni < 2; ++ni)
#pragma unroll
      for (int ks = 0; ks < 2; ++ks)
        blo[ni][ks] = *(const bf16x8*)&LB[ni * 1024 + ks * 512 + swzb];
    if (t + 1 < nt) { stageB(0, t + 1, buf ^ 1); stageB(1, t + 1, buf ^ 1); }
    __builtin_amdgcn_s_barrier();
    asm volatile("s_waitcnt lgkmcnt(0)" ::: "memory");
    __builtin_amdgcn_s_setprio(1);
#pragma unroll
    for (int mi = 0; mi < 4; ++mi)
#pragma unroll
      for (int ni = 0; ni < 2; ++ni)
#pragma unroll
        for (int ks = 0; ks < 2; ++ks)
          acc[mi][ni] = mfma16(a[mi][ks], blo[ni][ks], acc[mi][ni]);
    __builtin_amdgcn_s_setprio(0);
    __builtin_amdgcn_s_barrier();

    // ---- p1: read B-hi(4); stage A(t+2) -> buf; vmcnt(2); MFMA n-hi ----
#pragma unroll
    for (int ni = 0; ni < 2; ++ni)
#pragma unroll
      for (int ks = 0; ks < 2; ++ks)
        bhi[ni][ks] = *(const bf16x8*)&LB[(2 + ni) * 1024 + ks * 512 + swzb];
    if (t + 2 < nt) {
      stageA(t + 2, buf);
      asm volatile("s_waitcnt vmcnt(2)" ::: "memory");
    } else {
      asm volatile("s_waitcnt vmcnt(0)" ::: "memory");
    }
    __builtin_amdgcn_s_barrier();
    asm volatile("s_waitcnt lgkmcnt(0)" ::: "memory");
    __builtin_amdgcn_s_setprio(1);
#pragma unroll
    for (int mi = 0; mi < 4; ++mi)
#pragma unroll
      for (int ni = 0; ni < 2; ++ni)
#pragma unroll
        for (int ks = 0; ks < 2; ++ks)
          acc[mi][2 + ni] = mfma16(a[mi][ks], bhi[ni][ks], acc[mi][2 + ni]);
    __builtin_amdgcn_s_setprio(0);
    __builtin_amdgcn_s_barrier();
  }

  const int r0 = (lane >> 4) << 2, c0 = lane & 15;
  const int wrow = bm + (mh << 6), wcol = bn + (nq << 6);
#pragma unroll
  for (int ni = 0; ni < 4; ++ni) {
    const int col = wcol + (ni << 4) + c0;
    const float bv = bias[col];
#pragma unroll
    for (int mi = 0; mi < 4; ++mi) {
      const int row = wrow + (mi << 4) + r0;
#pragma unroll
      for (int r = 0; r < 4; ++r) {
        float v = acc[mi][ni][r] + bv;
        if (EPI == 1) v = 0.5f * v * (1.0f + erff(v * 0.70710678118654752f));
        if (OUTBF)
          Cb[(size_t)(row + r) * N + col] = (__bf16)v;
        else
          Cf[(size_t)(row + r) * N + col] = v;
      }
    }
  }
}

// ---------------------------------------------------------------------------
// Flash attention over fused QKV buffer [NTOK][2304]: q at col h*64,
// k at 768+h*64, v at 1536+h*64. One block per (h,b); K/V staged in LDS.
// ---------------------------------------------------------------------------
__global__ __launch_bounds__(256) void attn_kernel(const __bf16* __restrict__ qkv,
                                                   const int* __restrict__ amask,
                                                   __bf16* __restrict__ ctx) {
  __shared__ __bf16 Kl[S_][72];        // [key][d]  (pad 64->72)
  __shared__ __bf16 Vt[DH_][S_ + 8];   // [d][key]  (pad 512->520)
  __shared__ float extm[S_];
  __shared__ __bf16 Pl[4][16][56];     // per-wave P tile (pad 32->56)
  const int h = blockIdx.x, b = blockIdx.y;
  const int tid = threadIdx.x, wid = tid >> 6, lane = tid & 63;
  const size_t rowb = (size_t)b * S_ * QKVN + (size_t)h * DH_;

  for (int c = tid; c < S_ * DH_ / 8; c += 256) {
    const int s = c >> 3, d8 = (c & 7) << 3;
    bf16x8 kv = *(const bf16x8*)(qkv + rowb + (size_t)s * QKVN + H_ + d8);
    *(bf16x8*)&Kl[s][d8] = kv;
    bf16x8 vv = *(const bf16x8*)(qkv + rowb + (size_t)s * QKVN + 2 * H_ + d8);
#pragma unroll
    for (int j = 0; j < 8; ++j) Vt[d8 + j][s] = vv[j];
  }
  for (int i = tid; i < S_; i += 256)
    extm[i] = (1.0f - (float)amask[b * S_ + i]) * -10000.0f;
  __syncthreads();

  const int c0 = lane & 15, g4 = lane >> 4;
  for (int qt = wid; qt < S_ / 16; qt += 4) {
    const __bf16* qrow = qkv + rowb + (size_t)(qt * 16 + c0) * QKVN + (g4 << 3);
    const bf16x8 qf0 = *(const bf16x8*)qrow;
    const bf16x8 qf1 = *(const bf16x8*)(qrow + 32);
    f32x4 oacc[4] = {};
    float mrow[4] = {-1e30f, -1e30f, -1e30f, -1e30f};
    float lsum[4] = {0.f, 0.f, 0.f, 0.f};

    for (int kt = 0; kt < 16; ++kt) {
      f32x4 sc[2];
#pragma unroll
      for (int f = 0; f < 2; ++f) {
        const int key = kt * 32 + f * 16 + c0;
        const bf16x8 kf0 = *(const bf16x8*)&Kl[key][g4 << 3];
        const bf16x8 kf1 = *(const bf16x8*)&Kl[key][32 + (g4 << 3)];
        f32x4 z = {};
        z = mfma16(qf0, kf0, z);
        z = mfma16(qf1, kf1, z);
        const float e = extm[key];
#pragma unroll
        for (int r = 0; r < 4; ++r) sc[f][r] = z[r] * 0.125f + e;
      }
      float al[4];
#pragma unroll
      for (int r = 0; r < 4; ++r) {
        float mx = fmaxf(sc[0][r], sc[1][r]);
        mx = fmaxf(mx, __shfl_xor(mx, 1, 64));
        mx = fmaxf(mx, __shfl_xor(mx, 2, 64));
        mx = fmaxf(mx, __shfl_xor(mx, 4, 64));
        mx = fmaxf(mx, __shfl_xor(mx, 8, 64));
        const float mn = fmaxf(mrow[r], mx);
        al[r] = __expf(mrow[r] - mn);
        mrow[r] = mn;
        const float p0 = __expf(sc[0][r] - mn);
        const float p1 = __expf(sc[1][r] - mn);
        sc[0][r] = p0; sc[1][r] = p1;
        float rs = p0 + p1;
        rs += __shfl_xor(rs, 1, 64);
        rs += __shfl_xor(rs, 2, 64);
        rs += __shfl_xor(rs, 4, 64);
        rs += __shfl_xor(rs, 8, 64);
        lsum[r] = lsum[r] * al[r] + rs;
      }
#pragma unroll
      for (int f = 0; f < 2; ++f)
#pragma unroll
        for (int r = 0; r < 4; ++r)
          Pl[wid][g4 * 4 + r][f * 16 + c0] = (__bf16)sc[f][r];
#pragma unroll
      for (int dt = 0; dt < 4; ++dt)
#pragma unroll
        for (int r = 0; r < 4; ++r) oacc[dt][r] *= al[r];
      const bf16x8 pa = *(const bf16x8*)&Pl[wid][c0][g4 << 3];
#pragma unroll
      for (int dt = 0; dt < 4; ++dt) {
        const bf16x8 vf =
            *(const bf16x8*)&Vt[dt * 16 + c0][kt * 32 + (g4 << 3)];
        oacc[dt] = mfma16(pa, vf, oacc[dt]);
      }
    }
    float inv[4];
#pragma unroll
    for (int r = 0; r < 4; ++r) inv[r] = 1.0f / lsum[r];
#pragma unroll
    for (int dt = 0; dt < 4; ++dt)
#pragma unroll
      for (int r = 0; r < 4; ++r)
        ctx[(size_t)b * S_ * H_ + (size_t)h * DH_ +
            (size_t)(qt * 16 + g4 * 4 + r) * H_ + dt * 16 + c0] =
            (__bf16)(oacc[dt][r] * inv[r]);
  }
}

// ---------------------------------------------------------------------------
// Residual add + LayerNorm, ONE WAVE PER TOKEN (no block barrier).
// 4 tokens per 256-thread block; float4 loads (12 f32/lane).
// ---------------------------------------------------------------------------
__global__ __launch_bounds__(256) void addln_kernel(float* __restrict__ x,
                                                    const float* __restrict__ t,
                                                    const float* __restrict__ g,
                                                    const float* __restrict__ bb,
                                                    __bf16* __restrict__ xb) {
  const int tok = blockIdx.x * 4 + (threadIdx.x >> 6);
  const int lane = threadIdx.x & 63;
  float* xr = x + (size_t)tok * H_;
  const float* tr = t + (size_t)tok * H_;
  f32x4 v[3];
  float s = 0.f, s2 = 0.f;
#pragma unroll
  for (int i = 0; i < 3; ++i) {
    const int off = lane * 4 + i * 256;
    f32x4 a = *(const f32x4*)&xr[off];
    f32x4 b = *(const f32x4*)&tr[off];
    v[i] = a + b;
#pragma unroll
    for (int r = 0; r < 4; ++r) { s += v[i][r]; s2 += v[i][r] * v[i][r]; }
  }
#pragma unroll
  for (int o = 32; o > 0; o >>= 1) {
    s += __shfl_xor(s, o, 64);
    s2 += __shfl_xor(s2, o, 64);
  }
  const float mean = s * (1.0f / 768.0f);
  const float var = s2 * (1.0f / 768.0f) - mean * mean;
  const float rstd = rsqrtf(var + 1e-12f);
  __bf16* xbr = xb + (size_t)tok * H_;
#pragma unroll
  for (int i = 0; i < 3; ++i) {
    const int off = lane * 4 + i * 256;
    f32x4 gv = *(const f32x4*)&g[off];
    f32x4 bv = *(const f32x4*)&bb[off];
    f32x4 y;
    bf16x4 yb;
#pragma unroll
    for (int r = 0; r < 4; ++r) {
      y[r] = (v[i][r] - mean) * rstd * gv[r] + bv[r];
      yb[r] = (__bf16)y[r];
    }
    *(f32x4*)&xr[off] = y;
    *(bf16x4*)&xbr[off] = yb;
  }
}

// ---------------------------------------------------------------------------
// Embedding (word/star select + pos + type) + LN.
// ---------------------------------------------------------------------------
__global__ __launch_bounds__(256) void embed_kernel(
    const int* __restrict__ ids, const int* __restrict__ tt,
    const float* __restrict__ we, const float* __restrict__ se,
    const float* __restrict__ pe, const float* __restrict__ te,
    const float* __restrict__ g, const float* __restrict__ bb,
    float* __restrict__ x, __bf16* __restrict__ xb) {
  const int tok = blockIdx.x, tid = threadIdx.x;
  const int sp = tok & (S_ - 1);
  const int id = ids[tok];
  const float* e = (id >= 30700) ? se + (size_t)(id - 30700) * H_
                                 : we + (size_t)id * H_;
  const float* pr = pe + (size_t)sp * H_;
  const float* ty = te + (size_t)tt[tok] * H_;
  float v0 = e[tid] + pr[tid] + ty[tid];
  float v1 = e[tid + 256] + pr[tid + 256] + ty[tid + 256];
  float v2 = e[tid + 512] + pr[tid + 512] + ty[tid + 512];
  float s = v0 + v1 + v2;
  float s2 = v0 * v0 + v1 * v1 + v2 * v2;
  __shared__ float red1[4], red2[4];
#pragma unroll
  for (int o = 32; o > 0; o >>= 1) {
    s += __shfl_xor(s, o, 64);
    s2 += __shfl_xor(s2, o, 64);
  }
  if ((tid & 63) == 0) { red1[tid >> 6] = s; red2[tid >> 6] = s2; }
  __syncthreads();
  s = red1[0] + red1[1] + red1[2] + red1[3];
  s2 = red2[0] + red2[1] + red2[2] + red2[3];
  const float mean = s * (1.0f / 768.0f);
  const float var = s2 * (1.0f / 768.0f) - mean * mean;
  const float rstd = rsqrtf(var + 1e-12f);
  float* xr = x + (size_t)tok * H_;
  __bf16* xbr = xb + (size_t)tok * H_;
  const float y0 = (v0 - mean) * rstd * g[tid] + bb[tid];
  const float y1 = (v1 - mean) * rstd * g[tid + 256] + bb[tid + 256];
  const float y2 = (v2 - mean) * rstd * g[tid + 512] + bb[tid + 512];
  xr[tid] = y0; xr[tid + 256] = y1; xr[tid + 512] = y2;
  xbr[tid] = (__bf16)y0; xbr[tid + 256] = (__bf16)y1; xbr[tid + 512] = (__bf16)y2;
}

// ---------------------------------------------------------------------------
// Pooler: pooled[b] = tanh(x[b,0,:] @ poolW + pool_b).
// ---------------------------------------------------------------------------
__global__ __launch_bounds__(256) void pool_kernel(const float* __restrict__ x,
                                                   const __bf16* __restrict__ wT,
                                                   const float* __restrict__ pb,
                                                   float* __restrict__ out) {
  const int b = blockIdx.x, tid = threadIdx.x;
  __shared__ float xr[H_];
  for (int i = tid; i < H_; i += 256) xr[i] = x[(size_t)b * S_ * H_ + i];
  __syncthreads();
  for (int n = tid; n < H_; n += 256) {
    const __bf16* w = wT + (size_t)n * H_;
    float acc = 0.f;
    for (int k = 0; k < H_; ++k) acc += xr[k] * (float)w[k];
    out[(size_t)b * H_ + n] = tanhf(acc + pb[n]);
  }
}

// ---------------------------------------------------------------------------
extern "C" void kernel_launch(void* const* d_in, const int* in_sizes, int n_in,
                              void* d_out, int out_size, void* d_ws,
                              size_t ws_size, hipStream_t stream) {
  (void)in_sizes; (void)n_in; (void)out_size;
  const int* ids = (const int*)d_in[0];
  const int* am = (const int*)d_in[1];
  const int* tt = (const int*)d_in[2];
  const float* we = (const float*)d_in[3];
  const float* se = (const float*)d_in[4];
  const float* pe = (const float*)d_in[5];
  const float* te = (const float*)d_in[6];
  const float* eg = (const float*)d_in[7];
  const float* ebb = (const float*)d_in[8];
  const float* Wq = (const float*)d_in[9];
  const float* bq = (const float*)d_in[10];
  const float* Wk = (const float*)d_in[11];
  const float* bk = (const float*)d_in[12];
  const float* Wv = (const float*)d_in[13];
  const float* bv = (const float*)d_in[14];
  const float* Wo = (const float*)d_in[15];
  const float* bo = (const float*)d_in[16];
  const float* g1 = (const float*)d_in[17];
  const float* b1 = (const float*)d_in[18];
  const float* Wi = (const float*)d_in[19];
  const float* bi = (const float*)d_in[20];
  const float* Wf = (const float*)d_in[21];
  const float* bf_ = (const float*)d_in[22];
  const float* g2 = (const float*)d_in[23];
  const float* b2 = (const float*)d_in[24];
  const float* pw = (const float*)d_in[25];
  const float* pb = (const float*)d_in[26];

  const size_t WQKV = (size_t)L_ * QKVN * H_;
  const size_t WSQ = (size_t)L_ * H_ * H_;
  const size_t WSF = (size_t)L_ * H_ * F_;
  __bf16* wqkv = (__bf16*)d_ws;
  __bf16* wTo_ = wqkv + WQKV;
  __bf16* wTi_ = wTo_ + WSQ;
  __bf16* wTf_ = wTi_ + WSF;
  __bf16* wTp_ = wTf_ + WSF;
  __bf16* xb = wTp_ + (size_t)H_ * H_;
  __bf16* qkvb = xb + (size_t)NTOK * H_;
  __bf16* cb = qkvb + (size_t)NTOK * QKVN;
  __bf16* mid = cb + (size_t)NTOK * H_;
  float* t0 = (float*)(mid + (size_t)NTOK * F_);
  float* bqkv = t0 + (size_t)NTOK * H_;
  const size_t needed = (size_t)((char*)(bqkv + (size_t)L_ * QKVN) - (char*)d_ws);
  if (ws_size < needed) return;  // insufficient scratch: visible failure

  float* x = (float*)d_out;
  float* pooled = x + (size_t)NTOK * H_;

  const dim3 tb(32, 8);
  const size_t zq = (size_t)QKVN * H_;
  transpose_k<<<dim3(24, 24, 12), tb, 0, stream>>>(Wq, wqkv, H_, H_, zq);
  transpose_k<<<dim3(24, 24, 12), tb, 0, stream>>>(Wk, wqkv + (size_t)H_ * H_, H_, H_, zq);
  transpose_k<<<dim3(24, 24, 12), tb, 0, stream>>>(Wv, wqkv + 2 * (size_t)H_ * H_, H_, H_, zq);
  transpose_k<<<dim3(24, 24, 12), tb, 0, stream>>>(Wo, wTo_, H_, H_, (size_t)H_ * H_);
  transpose_k<<<dim3(96, 24, 12), tb, 0, stream>>>(Wi, wTi_, H_, F_, (size_t)H_ * F_);
  transpose_k<<<dim3(24, 96, 12), tb, 0, stream>>>(Wf, wTf_, F_, H_, (size_t)H_ * F_);
  transpose_k<<<dim3(24, 24, 1), tb, 0, stream>>>(pw, wTp_, H_, H_, (size_t)H_ * H_);
  concat_bias<<<(L_ * QKVN + 255) / 256, 256, 0, stream>>>(bq, bk, bv, bqkv);

  embed_kernel<<<NTOK, 256, 0, stream>>>(ids, tt, we, se, pe, te, eg, ebb, x, xb);

  for (int l = 0; l < L_; ++l) {
    // fused QKV: [8192,2304], BM=128 -> 576 blocks
    gemm8n<0, 1><<<(NTOK / 128) * (QKVN / 256), 512, 0, stream>>>(
        xb, wqkv + (size_t)l * QKVN * H_, bqkv + (size_t)l * QKVN,
        nullptr, qkvb, NTOK, QKVN, H_, QKVN / 256);

    attn_kernel<<<dim3(NH_, B_), 256, 0, stream>>>(qkvb, am, cb);

    // attn-out: BM=128 -> 192 blocks
    gemm8n<0, 0><<<(NTOK / 128) * (H_ / 256), 512, 0, stream>>>(
        cb, wTo_ + (size_t)l * H_ * H_, bo + l * H_, t0, nullptr,
        NTOK, H_, H_, H_ / 256);
    addln_kernel<<<NTOK / 4, 256, 0, stream>>>(x, t0, g1 + l * H_, b1 + l * H_, xb);

    // FF1: BM=256 -> 384 blocks
    gemm8<1, 1><<<(NTOK / 256) * (F_ / 256), 512, 0, stream>>>(
        xb, wTi_ + (size_t)l * H_ * F_, bi + l * F_, nullptr, mid,
        NTOK, F_, H_, F_ / 256);
    // FF2: BM=128 -> 192 blocks
    gemm8n<0, 0><<<(NTOK / 128) * (H_ / 256), 512, 0, stream>>>(
        mid, wTf_ + (size_t)l * F_ * H_, bf_ + l * H_, t0, nullptr,
        NTOK, H_, F_, H_ / 256);
    addln_kernel<<<NTOK / 4, 256, 0, stream>>>(x, t0, g2 + l * H_, b2 + l * H_, xb);
  }

  pool_kernel<<<B_, 256, 0, stream>>>(x, wTp_, pb, pooled);
}

// Round 4
// 4418.263 us; speedup vs baseline: 1.1324x; 1.0087x over previous
//
#include <hip/hip_runtime.h>
#include <hip/hip_bf16.h>
#include <math.h>

// ---------------------------------------------------------------------------
// KVPLM Star Encoder: 12 layers, H=768, NH=12, F=3072, B=16, S=512.
// Round 4: all GEMMs on the 2-phase 128x256 kernel (measured ~2.5x the
// 4-phase 256^2 port on these shapes); attention split across 2 blocks/(b,h).
// ---------------------------------------------------------------------------

#define L_   12
#define H_   768
#define NH_  12
#define DH_  64
#define F_   3072
#define B_   16
#define S_   512
#define NTOK (B_ * S_)   // 8192
#define QKVN 2304

typedef __attribute__((ext_vector_type(8))) __bf16 bf16x8;
typedef __attribute__((ext_vector_type(4))) __bf16 bf16x4;
typedef __attribute__((ext_vector_type(4))) float  f32x4;

static __device__ __forceinline__ f32x4 mfma16(bf16x8 a, bf16x8 b, f32x4 c) {
  return __builtin_amdgcn_mfma_f32_16x16x32_bf16(a, b, c, 0, 0, 0);
}

static __device__ __forceinline__ void load_lds16(const void* g, void* l) {
  __builtin_amdgcn_global_load_lds(
      (const __attribute__((address_space(1))) void*)g,
      (__attribute__((address_space(3))) void*)l, 16, 0, 0);
}

// ---------------------------------------------------------------------------
// Weight transpose+convert: in fp32 [Z][R][C] -> out bf16 [Z (stride outZ)][C][R]
// ---------------------------------------------------------------------------
__global__ __launch_bounds__(256) void transpose_k(const float* __restrict__ in,
                                                   __bf16* __restrict__ out,
                                                   int R, int C, size_t outZ) {
  __shared__ float t[32][33];
  const int z = blockIdx.z;
  const float* inz = in + (size_t)z * R * C;
  __bf16* outz = out + (size_t)z * outZ;
  const int c0 = blockIdx.x * 32, r0 = blockIdx.y * 32;
  const int tx = threadIdx.x, ty = threadIdx.y;
#pragma unroll
  for (int i = 0; i < 32; i += 8)
    t[ty + i][tx] = inz[(size_t)(r0 + ty + i) * C + c0 + tx];
  __syncthreads();
#pragma unroll
  for (int i = 0; i < 32; i += 8)
    outz[(size_t)(c0 + ty + i) * R + r0 + tx] = (__bf16)t[tx][ty + i];
}

__global__ __launch_bounds__(256) void concat_bias(const float* __restrict__ bq,
                                                   const float* __restrict__ bk,
                                                   const float* __restrict__ bv,
                                                   float* __restrict__ o) {
  const int i = blockIdx.x * 256 + threadIdx.x;
  if (i >= L_ * QKVN) return;
  const int l = i / QKVN, j = i - l * QKVN;
  float v;
  if (j < H_) v = bq[l * H_ + j];
  else if (j < 2 * H_) v = bk[l * H_ + j - H_];
  else v = bv[l * H_ + j - 2 * H_];
  o[i] = v;
}

// ---------------------------------------------------------------------------
// 2-phase 128x256 GEMM (T1 XCD swizzle + T2 st_16x32 swizzle + counted vmcnt
// + T5 setprio). LDS 96 KiB: A 2x8192 el, B 2x16384 el.
// Staging: t.p0 -> B(t+1) (buf^1, free since (t-1).p1); t.p1 -> A(t+2) (buf,
// free after t.p0). vmcnt(2) at p1 (counted, never 0 mid-loop) guarantees
// tile t+1 fully resident. Prologue order: A0, B0h0, B0h1, A1; vmcnt(2).
// ---------------------------------------------------------------------------
template <int EPI, int OUTBF>
__global__ __launch_bounds__(512, 2) void gemm8n(const __bf16* __restrict__ A,
                                                 const __bf16* __restrict__ Bt,
                                                 const float* __restrict__ bias,
                                                 float* __restrict__ Cf,
                                                 __bf16* __restrict__ Cb,
                                                 int M, int N, int K, int Ntiles) {
  alignas(16) __shared__ __bf16 lds[49152];  // 96 KiB
  const int tid = threadIdx.x, wid = tid >> 6, lane = tid & 63;
  int bid = blockIdx.x;
  const int nwg = gridDim.x;
  if ((nwg & 7) == 0) bid = (bid & 7) * (nwg >> 3) + (bid >> 3);  // XCD swizzle
  const int bm = (bid / Ntiles) << 7, bn = (bid % Ntiles) << 8;
  const int nt = K >> 6;

  const __bf16* pA[2];
  const __bf16* pB[2];
#pragma unroll
  for (int j = 0; j < 2; ++j) {
    const int E = (j << 12) + tid * 8;          // linear LDS element
    const int Ep = E ^ (((E >> 8) & 1) << 4);   // logical element (st_16x32)
    const int r = ((Ep >> 10) << 4) | ((Ep >> 5) & 15);
    const int c = (((Ep >> 9) & 1) << 5) | (Ep & 31);
    pA[j] = A + (size_t)(bm + r) * K + c;
    pB[j] = Bt + (size_t)(bn + r) * K + c;
  }
  const size_t hstr = (size_t)128 * K;

  auto stageA = [&](int t, int buf) {
    __bf16* dst = &lds[buf * 8192 + (wid << 9)];
    load_lds16(pA[0] + (size_t)(t << 6), dst);
    load_lds16(pA[1] + (size_t)(t << 6), dst + 4096);
  };
  auto stageB = [&](int h, int t, int buf) {
    __bf16* dst = &lds[16384 + buf * 16384 + h * 8192 + (wid << 9)];
    const size_t goff = (size_t)h * hstr + (size_t)(t << 6);
    load_lds16(pB[0] + goff, dst);
    load_lds16(pB[1] + goff, dst + 4096);
  };

  const int frow = lane & 15, fk = (lane >> 4) << 3;
  const int swzb = (frow * 32 + fk) ^ (((frow >> 3) & 1) << 4);
  const int mh = wid >> 2, nq = wid & 3;  // 2 M-waves x 4 N-waves, 64x64 each

  f32x4 acc[4][4] = {};

  // prologue (order matters for vmcnt(2)): A0, B0h0, B0h1, A1
  stageA(0, 0); stageB(0, 0, 0); stageB(1, 0, 0);
  if (nt > 1) stageA(1, 1);
  asm volatile("s_waitcnt vmcnt(2)" ::: "memory");
  __builtin_amdgcn_s_barrier();

  for (int t = 0; t < nt; ++t) {
    const int buf = t & 1;
    const __bf16* LA = &lds[buf * 8192 + mh * 4096];
    const __bf16* LB = &lds[16384 + buf * 16384 + (nq >> 1) * 8192 + ((nq & 1) << 12)];
    bf16x8 a[4][2], blo[2][2], bhi[2][2];

    // ---- p0: read A(8) + B-lo(4); stage B(t+1) -> buf^1; MFMA n-lo ----
#pragma unroll
    for (int mi = 0; mi < 4; ++mi)
#pragma unroll
      for (int ks = 0; ks < 2; ++ks)
        a[mi][ks] = *(const bf16x8*)&LA[mi * 1024 + ks * 512 + swzb];
#pragma unroll
    for (int ni = 0; ni < 2; ++ni)
#pragma unroll
      for (int ks = 0; ks < 2; ++ks)
        blo[ni][ks] = *(const bf16x8*)&LB[ni * 1024 + ks * 512 + swzb];
    if (t + 1 < nt) { stageB(0, t + 1, buf ^ 1); stageB(1, t + 1, buf ^ 1); }
    __builtin_amdgcn_s_barrier();
    asm volatile("s_waitcnt lgkmcnt(0)" ::: "memory");
    __builtin_amdgcn_s_setprio(1);
#pragma unroll
    for (int mi = 0; mi < 4; ++mi)
#pragma unroll
      for (int ni = 0; ni < 2; ++ni)
#pragma unroll
        for (int ks = 0; ks < 2; ++ks)
          acc[mi][ni] = mfma16(a[mi][ks], blo[ni][ks], acc[mi][ni]);
    __builtin_amdgcn_s_setprio(0);
    __builtin_amdgcn_s_barrier();

    // ---- p1: read B-hi(4); stage A(t+2) -> buf; vmcnt(2); MFMA n-hi ----
#pragma unroll
    for (int ni = 0; ni < 2; ++ni)
#pragma unroll
      for (int ks = 0; ks < 2; ++ks)
        bhi[ni][ks] = *(const bf16x8*)&LB[(2 + ni) * 1024 + ks * 512 + swzb];
    if (t + 2 < nt) {
      stageA(t + 2, buf);
      asm volatile("s_waitcnt vmcnt(2)" ::: "memory");
    } else {
      asm volatile("s_waitcnt vmcnt(0)" ::: "memory");
    }
    __builtin_amdgcn_s_barrier();
    asm volatile("s_waitcnt lgkmcnt(0)" ::: "memory");
    __builtin_amdgcn_s_setprio(1);
#pragma unroll
    for (int mi = 0; mi < 4; ++mi)
#pragma unroll
      for (int ni = 0; ni < 2; ++ni)
#pragma unroll
        for (int ks = 0; ks < 2; ++ks)
          acc[mi][2 + ni] = mfma16(a[mi][ks], bhi[ni][ks], acc[mi][2 + ni]);
    __builtin_amdgcn_s_setprio(0);
    __builtin_amdgcn_s_barrier();
  }

  const int r0 = (lane >> 4) << 2, c0 = lane & 15;
  const int wrow = bm + (mh << 6), wcol = bn + (nq << 6);
#pragma unroll
  for (int ni = 0; ni < 4; ++ni) {
    const int col = wcol + (ni << 4) + c0;
    const float bv = bias[col];
#pragma unroll
    for (int mi = 0; mi < 4; ++mi) {
      const int row = wrow + (mi << 4) + r0;
#pragma unroll
      for (int r = 0; r < 4; ++r) {
        float v = acc[mi][ni][r] + bv;
        if (EPI == 1) v = 0.5f * v * (1.0f + erff(v * 0.70710678118654752f));
        if (OUTBF)
          Cb[(size_t)(row + r) * N + col] = (__bf16)v;
        else
          Cf[(size_t)(row + r) * N + col] = v;
      }
    }
  }
}

// ---------------------------------------------------------------------------
// Flash attention over fused QKV buffer [NTOK][2304]: q at col h*64,
// k at 768+h*64, v at 1536+h*64. Grid (NH, B, 2): each z-block handles half
// the q-tiles (K/V staged per block; doubles chip fill 192->384 blocks).
// ---------------------------------------------------------------------------
__global__ __launch_bounds__(256) void attn_kernel(const __bf16* __restrict__ qkv,
                                                   const int* __restrict__ amask,
                                                   __bf16* __restrict__ ctx) {
  __shared__ __bf16 Kl[S_][72];        // [key][d]  (pad 64->72)
  __shared__ __bf16 Vt[DH_][S_ + 8];   // [d][key]  (pad 512->520)
  __shared__ float extm[S_];
  __shared__ __bf16 Pl[4][16][56];     // per-wave P tile (pad 32->56)
  const int h = blockIdx.x, b = blockIdx.y, z = blockIdx.z;
  const int tid = threadIdx.x, wid = tid >> 6, lane = tid & 63;
  const size_t rowb = (size_t)b * S_ * QKVN + (size_t)h * DH_;

  for (int c = tid; c < S_ * DH_ / 8; c += 256) {
    const int s = c >> 3, d8 = (c & 7) << 3;
    bf16x8 kv = *(const bf16x8*)(qkv + rowb + (size_t)s * QKVN + H_ + d8);
    *(bf16x8*)&Kl[s][d8] = kv;
    bf16x8 vv = *(const bf16x8*)(qkv + rowb + (size_t)s * QKVN + 2 * H_ + d8);
#pragma unroll
    for (int j = 0; j < 8; ++j) Vt[d8 + j][s] = vv[j];
  }
  for (int i = tid; i < S_; i += 256)
    extm[i] = (1.0f - (float)amask[b * S_ + i]) * -10000.0f;
  __syncthreads();

  const int c0 = lane & 15, g4 = lane >> 4;
  for (int qt = z * 4 + wid; qt < S_ / 16; qt += 8) {
    const __bf16* qrow = qkv + rowb + (size_t)(qt * 16 + c0) * QKVN + (g4 << 3);
    const bf16x8 qf0 = *(const bf16x8*)qrow;
    const bf16x8 qf1 = *(const bf16x8*)(qrow + 32);
    f32x4 oacc[4] = {};
    float mrow[4] = {-1e30f, -1e30f, -1e30f, -1e30f};
    float lsum[4] = {0.f, 0.f, 0.f, 0.f};

    for (int kt = 0; kt < 16; ++kt) {
      f32x4 sc[2];
#pragma unroll
      for (int f = 0; f < 2; ++f) {
        const int key = kt * 32 + f * 16 + c0;
        const bf16x8 kf0 = *(const bf16x8*)&Kl[key][g4 << 3];
        const bf16x8 kf1 = *(const bf16x8*)&Kl[key][32 + (g4 << 3)];
        f32x4 z2 = {};
        z2 = mfma16(qf0, kf0, z2);
        z2 = mfma16(qf1, kf1, z2);
        const float e = extm[key];
#pragma unroll
        for (int r = 0; r < 4; ++r) sc[f][r] = z2[r] * 0.125f + e;
      }
      float al[4];
#pragma unroll
      for (int r = 0; r < 4; ++r) {
        float mx = fmaxf(sc[0][r], sc[1][r]);
        mx = fmaxf(mx, __shfl_xor(mx, 1, 64));
        mx = fmaxf(mx, __shfl_xor(mx, 2, 64));
        mx = fmaxf(mx, __shfl_xor(mx, 4, 64));
        mx = fmaxf(mx, __shfl_xor(mx, 8, 64));
        const float mn = fmaxf(mrow[r], mx);
        al[r] = __expf(mrow[r] - mn);
        mrow[r] = mn;
        const float p0 = __expf(sc[0][r] - mn);
        const float p1 = __expf(sc[1][r] - mn);
        sc[0][r] = p0; sc[1][r] = p1;
        float rs = p0 + p1;
        rs += __shfl_xor(rs, 1, 64);
        rs += __shfl_xor(rs, 2, 64);
        rs += __shfl_xor(rs, 4, 64);
        rs += __shfl_xor(rs, 8, 64);
        lsum[r] = lsum[r] * al[r] + rs;
      }
#pragma unroll
      for (int f = 0; f < 2; ++f)
#pragma unroll
        for (int r = 0; r < 4; ++r)
          Pl[wid][g4 * 4 + r][f * 16 + c0] = (__bf16)sc[f][r];
#pragma unroll
      for (int dt = 0; dt < 4; ++dt)
#pragma unroll
        for (int r = 0; r < 4; ++r) oacc[dt][r] *= al[r];
      const bf16x8 pa = *(const bf16x8*)&Pl[wid][c0][g4 << 3];
#pragma unroll
      for (int dt = 0; dt < 4; ++dt) {
        const bf16x8 vf =
            *(const bf16x8*)&Vt[dt * 16 + c0][kt * 32 + (g4 << 3)];
        oacc[dt] = mfma16(pa, vf, oacc[dt]);
      }
    }
    float inv[4];
#pragma unroll
    for (int r = 0; r < 4; ++r) inv[r] = 1.0f / lsum[r];
#pragma unroll
    for (int dt = 0; dt < 4; ++dt)
#pragma unroll
      for (int r = 0; r < 4; ++r)
        ctx[(size_t)b * S_ * H_ + (size_t)h * DH_ +
            (size_t)(qt * 16 + g4 * 4 + r) * H_ + dt * 16 + c0] =
            (__bf16)(oacc[dt][r] * inv[r]);
  }
}

// ---------------------------------------------------------------------------
// Residual add + LayerNorm, ONE WAVE PER TOKEN (no block barrier).
// ---------------------------------------------------------------------------
__global__ __launch_bounds__(256) void addln_kernel(float* __restrict__ x,
                                                    const float* __restrict__ t,
                                                    const float* __restrict__ g,
                                                    const float* __restrict__ bb,
                                                    __bf16* __restrict__ xb) {
  const int tok = blockIdx.x * 4 + (threadIdx.x >> 6);
  const int lane = threadIdx.x & 63;
  float* xr = x + (size_t)tok * H_;
  const float* tr = t + (size_t)tok * H_;
  f32x4 v[3];
  float s = 0.f, s2 = 0.f;
#pragma unroll
  for (int i = 0; i < 3; ++i) {
    const int off = lane * 4 + i * 256;
    f32x4 a = *(const f32x4*)&xr[off];
    f32x4 b = *(const f32x4*)&tr[off];
    v[i] = a + b;
#pragma unroll
    for (int r = 0; r < 4; ++r) { s += v[i][r]; s2 += v[i][r] * v[i][r]; }
  }
#pragma unroll
  for (int o = 32; o > 0; o >>= 1) {
    s += __shfl_xor(s, o, 64);
    s2 += __shfl_xor(s2, o, 64);
  }
  const float mean = s * (1.0f / 768.0f);
  const float var = s2 * (1.0f / 768.0f) - mean * mean;
  const float rstd = rsqrtf(var + 1e-12f);
  __bf16* xbr = xb + (size_t)tok * H_;
#pragma unroll
  for (int i = 0; i < 3; ++i) {
    const int off = lane * 4 + i * 256;
    f32x4 gv = *(const f32x4*)&g[off];
    f32x4 bv = *(const f32x4*)&bb[off];
    f32x4 y;
    bf16x4 yb;
#pragma unroll
    for (int r = 0; r < 4; ++r) {
      y[r] = (v[i][r] - mean) * rstd * gv[r] + bv[r];
      yb[r] = (__bf16)y[r];
    }
    *(f32x4*)&xr[off] = y;
    *(bf16x4*)&xbr[off] = yb;
  }
}

// ---------------------------------------------------------------------------
// Embedding (word/star select + pos + type) + LN.
// ---------------------------------------------------------------------------
__global__ __launch_bounds__(256) void embed_kernel(
    const int* __restrict__ ids, const int* __restrict__ tt,
    const float* __restrict__ we, const float* __restrict__ se,
    const float* __restrict__ pe, const float* __restrict__ te,
    const float* __restrict__ g, const float* __restrict__ bb,
    float* __restrict__ x, __bf16* __restrict__ xb) {
  const int tok = blockIdx.x, tid = threadIdx.x;
  const int sp = tok & (S_ - 1);
  const int id = ids[tok];
  const float* e = (id >= 30700) ? se + (size_t)(id - 30700) * H_
                                 : we + (size_t)id * H_;
  const float* pr = pe + (size_t)sp * H_;
  const float* ty = te + (size_t)tt[tok] * H_;
  float v0 = e[tid] + pr[tid] + ty[tid];
  float v1 = e[tid + 256] + pr[tid + 256] + ty[tid + 256];
  float v2 = e[tid + 512] + pr[tid + 512] + ty[tid + 512];
  float s = v0 + v1 + v2;
  float s2 = v0 * v0 + v1 * v1 + v2 * v2;
  __shared__ float red1[4], red2[4];
#pragma unroll
  for (int o = 32; o > 0; o >>= 1) {
    s += __shfl_xor(s, o, 64);
    s2 += __shfl_xor(s2, o, 64);
  }
  if ((tid & 63) == 0) { red1[tid >> 6] = s; red2[tid >> 6] = s2; }
  __syncthreads();
  s = red1[0] + red1[1] + red1[2] + red1[3];
  s2 = red2[0] + red2[1] + red2[2] + red2[3];
  const float mean = s * (1.0f / 768.0f);
  const float var = s2 * (1.0f / 768.0f) - mean * mean;
  const float rstd = rsqrtf(var + 1e-12f);
  float* xr = x + (size_t)tok * H_;
  __bf16* xbr = xb + (size_t)tok * H_;
  const float y0 = (v0 - mean) * rstd * g[tid] + bb[tid];
  const float y1 = (v1 - mean) * rstd * g[tid + 256] + bb[tid + 256];
  const float y2 = (v2 - mean) * rstd * g[tid + 512] + bb[tid + 512];
  xr[tid] = y0; xr[tid + 256] = y1; xr[tid + 512] = y2;
  xbr[tid] = (__bf16)y0; xbr[tid + 256] = (__bf16)y1; xbr[tid + 512] = (__bf16)y2;
}

// ---------------------------------------------------------------------------
// Pooler: pooled[b] = tanh(x[b,0,:] @ poolW + pool_b).
// ---------------------------------------------------------------------------
__global__ __launch_bounds__(256) void pool_kernel(const float* __restrict__ x,
                                                   const __bf16* __restrict__ wT,
                                                   const float* __restrict__ pb,
                                                   float* __restrict__ out) {
  const int b = blockIdx.x, tid = threadIdx.x;
  __shared__ float xr[H_];
  for (int i = tid; i < H_; i += 256) xr[i] = x[(size_t)b * S_ * H_ + i];
  __syncthreads();
  for (int n = tid; n < H_; n += 256) {
    const __bf16* w = wT + (size_t)n * H_;
    float acc = 0.f;
    for (int k = 0; k < H_; ++k) acc += xr[k] * (float)w[k];
    out[(size_t)b * H_ + n] = tanhf(acc + pb[n]);
  }
}

// ---------------------------------------------------------------------------
extern "C" void kernel_launch(void* const* d_in, const int* in_sizes, int n_in,
                              void* d_out, int out_size, void* d_ws,
                              size_t ws_size, hipStream_t stream) {
  (void)in_sizes; (void)n_in; (void)out_size;
  const int* ids = (const int*)d_in[0];
  const int* am = (const int*)d_in[1];
  const int* tt = (const int*)d_in[2];
  const float* we = (const float*)d_in[3];
  const float* se = (const float*)d_in[4];
  const float* pe = (const float*)d_in[5];
  const float* te = (const float*)d_in[6];
  const float* eg = (const float*)d_in[7];
  const float* ebb = (const float*)d_in[8];
  const float* Wq = (const float*)d_in[9];
  const float* bq = (const float*)d_in[10];
  const float* Wk = (const float*)d_in[11];
  const float* bk = (const float*)d_in[12];
  const float* Wv = (const float*)d_in[13];
  const float* bv = (const float*)d_in[14];
  const float* Wo = (const float*)d_in[15];
  const float* bo = (const float*)d_in[16];
  const float* g1 = (const float*)d_in[17];
  const float* b1 = (const float*)d_in[18];
  const float* Wi = (const float*)d_in[19];
  const float* bi = (const float*)d_in[20];
  const float* Wf = (const float*)d_in[21];
  const float* bf_ = (const float*)d_in[22];
  const float* g2 = (const float*)d_in[23];
  const float* b2 = (const float*)d_in[24];
  const float* pw = (const float*)d_in[25];
  const float* pb = (const float*)d_in[26];

  const size_t WQKV = (size_t)L_ * QKVN * H_;
  const size_t WSQ = (size_t)L_ * H_ * H_;
  const size_t WSF = (size_t)L_ * H_ * F_;
  __bf16* wqkv = (__bf16*)d_ws;
  __bf16* wTo_ = wqkv + WQKV;
  __bf16* wTi_ = wTo_ + WSQ;
  __bf16* wTf_ = wTi_ + WSF;
  __bf16* wTp_ = wTf_ + WSF;
  __bf16* xb = wTp_ + (size_t)H_ * H_;
  __bf16* qkvb = xb + (size_t)NTOK * H_;
  __bf16* cb = qkvb + (size_t)NTOK * QKVN;
  __bf16* mid = cb + (size_t)NTOK * H_;
  float* t0 = (float*)(mid + (size_t)NTOK * F_);
  float* bqkv = t0 + (size_t)NTOK * H_;
  const size_t needed = (size_t)((char*)(bqkv + (size_t)L_ * QKVN) - (char*)d_ws);
  if (ws_size < needed) return;  // insufficient scratch: visible failure

  float* x = (float*)d_out;
  float* pooled = x + (size_t)NTOK * H_;

  const dim3 tb(32, 8);
  const size_t zq = (size_t)QKVN * H_;
  transpose_k<<<dim3(24, 24, 12), tb, 0, stream>>>(Wq, wqkv, H_, H_, zq);
  transpose_k<<<dim3(24, 24, 12), tb, 0, stream>>>(Wk, wqkv + (size_t)H_ * H_, H_, H_, zq);
  transpose_k<<<dim3(24, 24, 12), tb, 0, stream>>>(Wv, wqkv + 2 * (size_t)H_ * H_, H_, H_, zq);
  transpose_k<<<dim3(24, 24, 12), tb, 0, stream>>>(Wo, wTo_, H_, H_, (size_t)H_ * H_);
  transpose_k<<<dim3(96, 24, 12), tb, 0, stream>>>(Wi, wTi_, H_, F_, (size_t)H_ * F_);
  transpose_k<<<dim3(24, 96, 12), tb, 0, stream>>>(Wf, wTf_, F_, H_, (size_t)H_ * F_);
  transpose_k<<<dim3(24, 24, 1), tb, 0, stream>>>(pw, wTp_, H_, H_, (size_t)H_ * H_);
  concat_bias<<<(L_ * QKVN + 255) / 256, 256, 0, stream>>>(bq, bk, bv, bqkv);

  embed_kernel<<<NTOK, 256, 0, stream>>>(ids, tt, we, se, pe, te, eg, ebb, x, xb);

  for (int l = 0; l < L_; ++l) {
    // fused QKV: [8192,2304], BM=128 -> 576 blocks
    gemm8n<0, 1><<<(NTOK / 128) * (QKVN / 256), 512, 0, stream>>>(
        xb, wqkv + (size_t)l * QKVN * H_, bqkv + (size_t)l * QKVN,
        nullptr, qkvb, NTOK, QKVN, H_, QKVN / 256);

    attn_kernel<<<dim3(NH_, B_, 2), 256, 0, stream>>>(qkvb, am, cb);

    // attn-out: 192 blocks
    gemm8n<0, 0><<<(NTOK / 128) * (H_ / 256), 512, 0, stream>>>(
        cb, wTo_ + (size_t)l * H_ * H_, bo + l * H_, t0, nullptr,
        NTOK, H_, H_, H_ / 256);
    addln_kernel<<<NTOK / 4, 256, 0, stream>>>(x, t0, g1 + l * H_, b1 + l * H_, xb);

    // FF1: 768 blocks (was 4-phase 256^2 at 384; 2-phase measured faster)
    gemm8n<1, 1><<<(NTOK / 128) * (F_ / 256), 512, 0, stream>>>(
        xb, wTi_ + (size_t)l * H_ * F_, bi + l * F_, nullptr, mid,
        NTOK, F_, H_, F_ / 256);
    // FF2: 192 blocks
    gemm8n<0, 0><<<(NTOK / 128) * (H_ / 256), 512, 0, stream>>>(
        mid, wTf_ + (size_t)l * F_ * H_, bf_ + l * H_, t0, nullptr,
        NTOK, H_, F_, H_ / 256);
    addln_kernel<<<NTOK / 4, 256, 0, stream>>>(x, t0, g2 + l * H_, b2 + l * H_, xb);
  }

  pool_kernel<<<B_, 256, 0, stream>>>(x, wTp_, pb, pooled);
}

// Round 5
// 4245.515 us; speedup vs baseline: 1.1785x; 1.0407x over previous
//
#include <hip/hip_runtime.h>
#include <hip/hip_bf16.h>
#include <math.h>

// ---------------------------------------------------------------------------
// KVPLM Star Encoder: 12 layers, H=768, NH=12, F=3072, B=16, S=512.
// Round 5: staging-free attention (K and pre-transposed V^T read straight
// from L2-resident global; LDS only for mask + P tile), grid 768 = 3/CU.
// GEMMs unchanged (2-phase 128x256, proven in R3/R4).
// ---------------------------------------------------------------------------

#define L_   12
#define H_   768
#define NH_  12
#define DH_  64
#define F_   3072
#define B_   16
#define S_   512
#define NTOK (B_ * S_)   // 8192
#define QKVN 2304

typedef __attribute__((ext_vector_type(8))) __bf16 bf16x8;
typedef __attribute__((ext_vector_type(4))) __bf16 bf16x4;
typedef __attribute__((ext_vector_type(4))) float  f32x4;

static __device__ __forceinline__ f32x4 mfma16(bf16x8 a, bf16x8 b, f32x4 c) {
  return __builtin_amdgcn_mfma_f32_16x16x32_bf16(a, b, c, 0, 0, 0);
}

static __device__ __forceinline__ void load_lds16(const void* g, void* l) {
  __builtin_amdgcn_global_load_lds(
      (const __attribute__((address_space(1))) void*)g,
      (__attribute__((address_space(3))) void*)l, 16, 0, 0);
}

// ---------------------------------------------------------------------------
// Weight transpose+convert: in fp32 [Z][R][C] -> out bf16 [Z (stride outZ)][C][R]
// ---------------------------------------------------------------------------
__global__ __launch_bounds__(256) void transpose_k(const float* __restrict__ in,
                                                   __bf16* __restrict__ out,
                                                   int R, int C, size_t outZ) {
  __shared__ float t[32][33];
  const int z = blockIdx.z;
  const float* inz = in + (size_t)z * R * C;
  __bf16* outz = out + (size_t)z * outZ;
  const int c0 = blockIdx.x * 32, r0 = blockIdx.y * 32;
  const int tx = threadIdx.x, ty = threadIdx.y;
#pragma unroll
  for (int i = 0; i < 32; i += 8)
    t[ty + i][tx] = inz[(size_t)(r0 + ty + i) * C + c0 + tx];
  __syncthreads();
#pragma unroll
  for (int i = 0; i < 32; i += 8)
    outz[(size_t)(c0 + ty + i) * R + r0 + tx] = (__bf16)t[tx][ty + i];
}

__global__ __launch_bounds__(256) void concat_bias(const float* __restrict__ bq,
                                                   const float* __restrict__ bk,
                                                   const float* __restrict__ bv,
                                                   float* __restrict__ o) {
  const int i = blockIdx.x * 256 + threadIdx.x;
  if (i >= L_ * QKVN) return;
  const int l = i / QKVN, j = i - l * QKVN;
  float v;
  if (j < H_) v = bq[l * H_ + j];
  else if (j < 2 * H_) v = bk[l * H_ + j - H_];
  else v = bv[l * H_ + j - 2 * H_];
  o[i] = v;
}

// ---------------------------------------------------------------------------
// V transpose (per layer): qkv [NTOK][2304] cols 1536+ -> vt [(b*NH+h)*64+d][512]
// 32x32 bf16 LDS tiles, coalesced reads and writes. Grid (16, 2, B*NH).
// ---------------------------------------------------------------------------
__global__ __launch_bounds__(256) void vtrans_kernel(const __bf16* __restrict__ qkv,
                                                     __bf16* __restrict__ vt) {
  __shared__ __bf16 t[32][36];  // 36: 18-dword row pitch -> 2-way (free)
  const int bh = blockIdx.z;           // b*NH + h
  const int bb = bh / NH_, hh = bh - bb * NH_;
  const int s0 = blockIdx.x * 32, d0 = blockIdx.y * 32;
  const int tx = threadIdx.x, ty = threadIdx.y;
  const __bf16* src = qkv + (size_t)(bb * S_) * QKVN + 2 * H_ + hh * DH_;
#pragma unroll
  for (int i = 0; i < 32; i += 8)
    t[ty + i][tx] = src[(size_t)(s0 + ty + i) * QKVN + d0 + tx];
  __syncthreads();
  __bf16* dst = vt + ((size_t)bh * DH_) * S_;
#pragma unroll
  for (int i = 0; i < 32; i += 8)
    dst[(size_t)(d0 + ty + i) * S_ + s0 + tx] = t[tx][ty + i];
}

// ---------------------------------------------------------------------------
// 2-phase 128x256 GEMM (T1 XCD swizzle + T2 st_16x32 swizzle + counted vmcnt
// + T5 setprio). LDS 96 KiB: A 2x8192 el, B 2x16384 el.  (unchanged R3/R4)
// ---------------------------------------------------------------------------
template <int EPI, int OUTBF>
__global__ __launch_bounds__(512, 2) void gemm8n(const __bf16* __restrict__ A,
                                                 const __bf16* __restrict__ Bt,
                                                 const float* __restrict__ bias,
                                                 float* __restrict__ Cf,
                                                 __bf16* __restrict__ Cb,
                                                 int M, int N, int K, int Ntiles) {
  alignas(16) __shared__ __bf16 lds[49152];  // 96 KiB
  const int tid = threadIdx.x, wid = tid >> 6, lane = tid & 63;
  int bid = blockIdx.x;
  const int nwg = gridDim.x;
  if ((nwg & 7) == 0) bid = (bid & 7) * (nwg >> 3) + (bid >> 3);  // XCD swizzle
  const int bm = (bid / Ntiles) << 7, bn = (bid % Ntiles) << 8;
  const int nt = K >> 6;

  const __bf16* pA[2];
  const __bf16* pB[2];
#pragma unroll
  for (int j = 0; j < 2; ++j) {
    const int E = (j << 12) + tid * 8;          // linear LDS element
    const int Ep = E ^ (((E >> 8) & 1) << 4);   // logical element (st_16x32)
    const int r = ((Ep >> 10) << 4) | ((Ep >> 5) & 15);
    const int c = (((Ep >> 9) & 1) << 5) | (Ep & 31);
    pA[j] = A + (size_t)(bm + r) * K + c;
    pB[j] = Bt + (size_t)(bn + r) * K + c;
  }
  const size_t hstr = (size_t)128 * K;

  auto stageA = [&](int t, int buf) {
    __bf16* dst = &lds[buf * 8192 + (wid << 9)];
    load_lds16(pA[0] + (size_t)(t << 6), dst);
    load_lds16(pA[1] + (size_t)(t << 6), dst + 4096);
  };
  auto stageB = [&](int h, int t, int buf) {
    __bf16* dst = &lds[16384 + buf * 16384 + h * 8192 + (wid << 9)];
    const size_t goff = (size_t)h * hstr + (size_t)(t << 6);
    load_lds16(pB[0] + goff, dst);
    load_lds16(pB[1] + goff, dst + 4096);
  };

  const int frow = lane & 15, fk = (lane >> 4) << 3;
  const int swzb = (frow * 32 + fk) ^ (((frow >> 3) & 1) << 4);
  const int mh = wid >> 2, nq = wid & 3;  // 2 M-waves x 4 N-waves, 64x64 each

  f32x4 acc[4][4] = {};

  // prologue (order matters for vmcnt(2)): A0, B0h0, B0h1, A1
  stageA(0, 0); stageB(0, 0, 0); stageB(1, 0, 0);
  if (nt > 1) stageA(1, 1);
  asm volatile("s_waitcnt vmcnt(2)" ::: "memory");
  __builtin_amdgcn_s_barrier();

  for (int t = 0; t < nt; ++t) {
    const int buf = t & 1;
    const __bf16* LA = &lds[buf * 8192 + mh * 4096];
    const __bf16* LB = &lds[16384 + buf * 16384 + (nq >> 1) * 8192 + ((nq & 1) << 12)];
    bf16x8 a[4][2], blo[2][2], bhi[2][2];

    // ---- p0: read A(8) + B-lo(4); stage B(t+1) -> buf^1; MFMA n-lo ----
#pragma unroll
    for (int mi = 0; mi < 4; ++mi)
#pragma unroll
      for (int ks = 0; ks < 2; ++ks)
        a[mi][ks] = *(const bf16x8*)&LA[mi * 1024 + ks * 512 + swzb];
#pragma unroll
    for (int ni = 0; ni < 2; ++ni)
#pragma unroll
      for (int ks = 0; ks < 2; ++ks)
        blo[ni][ks] = *(const bf16x8*)&LB[ni * 1024 + ks * 512 + swzb];
    if (t + 1 < nt) { stageB(0, t + 1, buf ^ 1); stageB(1, t + 1, buf ^ 1); }
    __builtin_amdgcn_s_barrier();
    asm volatile("s_waitcnt lgkmcnt(0)" ::: "memory");
    __builtin_amdgcn_s_setprio(1);
#pragma unroll
    for (int mi = 0; mi < 4; ++mi)
#pragma unroll
      for (int ni = 0; ni < 2; ++ni)
#pragma unroll
        for (int ks = 0; ks < 2; ++ks)
          acc[mi][ni] = mfma16(a[mi][ks], blo[ni][ks], acc[mi][ni]);
    __builtin_amdgcn_s_setprio(0);
    __builtin_amdgcn_s_barrier();

    // ---- p1: read B-hi(4); stage A(t+2) -> buf; vmcnt(2); MFMA n-hi ----
#pragma unroll
    for (int ni = 0; ni < 2; ++ni)
#pragma unroll
      for (int ks = 0; ks < 2; ++ks)
        bhi[ni][ks] = *(const bf16x8*)&LB[(2 + ni) * 1024 + ks * 512 + swzb];
    if (t + 2 < nt) {
      stageA(t + 2, buf);
      asm volatile("s_waitcnt vmcnt(2)" ::: "memory");
    } else {
      asm volatile("s_waitcnt vmcnt(0)" ::: "memory");
    }
    __builtin_amdgcn_s_barrier();
    asm volatile("s_waitcnt lgkmcnt(0)" ::: "memory");
    __builtin_amdgcn_s_setprio(1);
#pragma unroll
    for (int mi = 0; mi < 4; ++mi)
#pragma unroll
      for (int ni = 0; ni < 2; ++ni)
#pragma unroll
        for (int ks = 0; ks < 2; ++ks)
          acc[mi][2 + ni] = mfma16(a[mi][ks], bhi[ni][ks], acc[mi][2 + ni]);
    __builtin_amdgcn_s_setprio(0);
    __builtin_amdgcn_s_barrier();
  }

  const int r0 = (lane >> 4) << 2, c0 = lane & 15;
  const int wrow = bm + (mh << 6), wcol = bn + (nq << 6);
#pragma unroll
  for (int ni = 0; ni < 4; ++ni) {
    const int col = wcol + (ni << 4) + c0;
    const float bv = bias[col];
#pragma unroll
    for (int mi = 0; mi < 4; ++mi) {
      const int row = wrow + (mi << 4) + r0;
#pragma unroll
      for (int r = 0; r < 4; ++r) {
        float v = acc[mi][ni][r] + bv;
        if (EPI == 1) v = 0.5f * v * (1.0f + erff(v * 0.70710678118654752f));
        if (OUTBF)
          Cb[(size_t)(row + r) * N + col] = (__bf16)v;
        else
          Cf[(size_t)(row + r) * N + col] = v;
      }
    }
  }
}

// ---------------------------------------------------------------------------
// Flash attention, staging-free: Q,K rows read from qkv [NTOK][2304]; V read
// from pre-transposed vt [(b*NH+h)*64+d][512]. K/V are L2-resident (128 KB
// per (b,h)) so LDS staging is pure overhead (guide mistake #7). LDS: mask +
// per-wave P tile only (9 KB). Grid (NH, B, 4) = 768 blocks = 3/CU.
// ---------------------------------------------------------------------------
__global__ __launch_bounds__(256, 3) void attn_kernel(const __bf16* __restrict__ qkv,
                                                      const __bf16* __restrict__ vt,
                                                      const int* __restrict__ amask,
                                                      __bf16* __restrict__ ctx) {
  __shared__ float extm[S_];
  __shared__ __bf16 Pl[4][16][56];     // per-wave P tile (pad 32->56)
  const int h = blockIdx.x, b = blockIdx.y, z = blockIdx.z;
  const int tid = threadIdx.x, wid = tid >> 6, lane = tid & 63;
  const size_t rowb = (size_t)b * S_ * QKVN + (size_t)h * DH_;
  const __bf16* vbase = vt + ((size_t)(b * NH_ + h) * DH_) * S_;

  for (int i = tid; i < S_; i += 256)
    extm[i] = (1.0f - (float)amask[b * S_ + i]) * -10000.0f;
  __syncthreads();

  const int c0 = lane & 15, g4 = lane >> 4;
  for (int qt = z * 4 + wid; qt < S_ / 16; qt += 16) {
    const __bf16* qrow = qkv + rowb + (size_t)(qt * 16 + c0) * QKVN + (g4 << 3);
    const bf16x8 qf0 = *(const bf16x8*)qrow;
    const bf16x8 qf1 = *(const bf16x8*)(qrow + 32);
    f32x4 oacc[4] = {};
    float mrow[4] = {-1e30f, -1e30f, -1e30f, -1e30f};
    float lsum[4] = {0.f, 0.f, 0.f, 0.f};

    for (int kt = 0; kt < 16; ++kt) {
      f32x4 sc[2];
#pragma unroll
      for (int f = 0; f < 2; ++f) {
        const int key = kt * 32 + f * 16 + c0;
        const __bf16* krow = qkv + rowb + (size_t)key * QKVN + H_ + (g4 << 3);
        const bf16x8 kf0 = *(const bf16x8*)krow;
        const bf16x8 kf1 = *(const bf16x8*)(krow + 32);
        f32x4 z2 = {};
        z2 = mfma16(qf0, kf0, z2);
        z2 = mfma16(qf1, kf1, z2);
        const float e = extm[key];
#pragma unroll
        for (int r = 0; r < 4; ++r) sc[f][r] = z2[r] * 0.125f + e;
      }
      float al[4];
#pragma unroll
      for (int r = 0; r < 4; ++r) {
        float mx = fmaxf(sc[0][r], sc[1][r]);
        mx = fmaxf(mx, __shfl_xor(mx, 1, 64));
        mx = fmaxf(mx, __shfl_xor(mx, 2, 64));
        mx = fmaxf(mx, __shfl_xor(mx, 4, 64));
        mx = fmaxf(mx, __shfl_xor(mx, 8, 64));
        const float mn = fmaxf(mrow[r], mx);
        al[r] = __expf(mrow[r] - mn);
        mrow[r] = mn;
        const float p0 = __expf(sc[0][r] - mn);
        const float p1 = __expf(sc[1][r] - mn);
        sc[0][r] = p0; sc[1][r] = p1;
        float rs = p0 + p1;
        rs += __shfl_xor(rs, 1, 64);
        rs += __shfl_xor(rs, 2, 64);
        rs += __shfl_xor(rs, 4, 64);
        rs += __shfl_xor(rs, 8, 64);
        lsum[r] = lsum[r] * al[r] + rs;
      }
#pragma unroll
      for (int f = 0; f < 2; ++f)
#pragma unroll
        for (int r = 0; r < 4; ++r)
          Pl[wid][g4 * 4 + r][f * 16 + c0] = (__bf16)sc[f][r];
#pragma unroll
      for (int dt = 0; dt < 4; ++dt)
#pragma unroll
        for (int r = 0; r < 4; ++r) oacc[dt][r] *= al[r];
      const bf16x8 pa = *(const bf16x8*)&Pl[wid][c0][g4 << 3];
#pragma unroll
      for (int dt = 0; dt < 4; ++dt) {
        const bf16x8 vf = *(const bf16x8*)&vbase[(size_t)(dt * 16 + c0) * S_ +
                                                kt * 32 + (g4 << 3)];
        oacc[dt] = mfma16(pa, vf, oacc[dt]);
      }
    }
    float inv[4];
#pragma unroll
    for (int r = 0; r < 4; ++r) inv[r] = 1.0f / lsum[r];
#pragma unroll
    for (int dt = 0; dt < 4; ++dt)
#pragma unroll
      for (int r = 0; r < 4; ++r)
        ctx[(size_t)b * S_ * H_ + (size_t)h * DH_ +
            (size_t)(qt * 16 + g4 * 4 + r) * H_ + dt * 16 + c0] =
            (__bf16)(oacc[dt][r] * inv[r]);
  }
}

// ---------------------------------------------------------------------------
// Residual add + LayerNorm, ONE WAVE PER TOKEN (no block barrier).
// ---------------------------------------------------------------------------
__global__ __launch_bounds__(256) void addln_kernel(float* __restrict__ x,
                                                    const float* __restrict__ t,
                                                    const float* __restrict__ g,
                                                    const float* __restrict__ bb,
                                                    __bf16* __restrict__ xb) {
  const int tok = blockIdx.x * 4 + (threadIdx.x >> 6);
  const int lane = threadIdx.x & 63;
  float* xr = x + (size_t)tok * H_;
  const float* tr = t + (size_t)tok * H_;
  f32x4 v[3];
  float s = 0.f, s2 = 0.f;
#pragma unroll
  for (int i = 0; i < 3; ++i) {
    const int off = lane * 4 + i * 256;
    f32x4 a = *(const f32x4*)&xr[off];
    f32x4 b = *(const f32x4*)&tr[off];
    v[i] = a + b;
#pragma unroll
    for (int r = 0; r < 4; ++r) { s += v[i][r]; s2 += v[i][r] * v[i][r]; }
  }
#pragma unroll
  for (int o = 32; o > 0; o >>= 1) {
    s += __shfl_xor(s, o, 64);
    s2 += __shfl_xor(s2, o, 64);
  }
  const float mean = s * (1.0f / 768.0f);
  const float var = s2 * (1.0f / 768.0f) - mean * mean;
  const float rstd = rsqrtf(var + 1e-12f);
  __bf16* xbr = xb + (size_t)tok * H_;
#pragma unroll
  for (int i = 0; i < 3; ++i) {
    const int off = lane * 4 + i * 256;
    f32x4 gv = *(const f32x4*)&g[off];
    f32x4 bv = *(const f32x4*)&bb[off];
    f32x4 y;
    bf16x4 yb;
#pragma unroll
    for (int r = 0; r < 4; ++r) {
      y[r] = (v[i][r] - mean) * rstd * gv[r] + bv[r];
      yb[r] = (__bf16)y[r];
    }
    *(f32x4*)&xr[off] = y;
    *(bf16x4*)&xbr[off] = yb;
  }
}

// ---------------------------------------------------------------------------
// Embedding (word/star select + pos + type) + LN.
// ---------------------------------------------------------------------------
__global__ __launch_bounds__(256) void embed_kernel(
    const int* __restrict__ ids, const int* __restrict__ tt,
    const float* __restrict__ we, const float* __restrict__ se,
    const float* __restrict__ pe, const float* __restrict__ te,
    const float* __restrict__ g, const float* __restrict__ bb,
    float* __restrict__ x, __bf16* __restrict__ xb) {
  const int tok = blockIdx.x, tid = threadIdx.x;
  const int sp = tok & (S_ - 1);
  const int id = ids[tok];
  const float* e = (id >= 30700) ? se + (size_t)(id - 30700) * H_
                                 : we + (size_t)id * H_;
  const float* pr = pe + (size_t)sp * H_;
  const float* ty = te + (size_t)tt[tok] * H_;
  float v0 = e[tid] + pr[tid] + ty[tid];
  float v1 = e[tid + 256] + pr[tid + 256] + ty[tid + 256];
  float v2 = e[tid + 512] + pr[tid + 512] + ty[tid + 512];
  float s = v0 + v1 + v2;
  float s2 = v0 * v0 + v1 * v1 + v2 * v2;
  __shared__ float red1[4], red2[4];
#pragma unroll
  for (int o = 32; o > 0; o >>= 1) {
    s += __shfl_xor(s, o, 64);
    s2 += __shfl_xor(s2, o, 64);
  }
  if ((tid & 63) == 0) { red1[tid >> 6] = s; red2[tid >> 6] = s2; }
  __syncthreads();
  s = red1[0] + red1[1] + red1[2] + red1[3];
  s2 = red2[0] + red2[1] + red2[2] + red2[3];
  const float mean = s * (1.0f / 768.0f);
  const float var = s2 * (1.0f / 768.0f) - mean * mean;
  const float rstd = rsqrtf(var + 1e-12f);
  float* xr = x + (size_t)tok * H_;
  __bf16* xbr = xb + (size_t)tok * H_;
  const float y0 = (v0 - mean) * rstd * g[tid] + bb[tid];
  const float y1 = (v1 - mean) * rstd * g[tid + 256] + bb[tid + 256];
  const float y2 = (v2 - mean) * rstd * g[tid + 512] + bb[tid + 512];
  xr[tid] = y0; xr[tid + 256] = y1; xr[tid + 512] = y2;
  xbr[tid] = (__bf16)y0; xbr[tid + 256] = (__bf16)y1; xbr[tid + 512] = (__bf16)y2;
}

// ---------------------------------------------------------------------------
// Pooler: pooled[b] = tanh(x[b,0,:] @ poolW + pool_b).
// ---------------------------------------------------------------------------
__global__ __launch_bounds__(256) void pool_kernel(const float* __restrict__ x,
                                                   const __bf16* __restrict__ wT,
                                                   const float* __restrict__ pb,
                                                   float* __restrict__ out) {
  const int b = blockIdx.x, tid = threadIdx.x;
  __shared__ float xr[H_];
  for (int i = tid; i < H_; i += 256) xr[i] = x[(size_t)b * S_ * H_ + i];
  __syncthreads();
  for (int n = tid; n < H_; n += 256) {
    const __bf16* w = wT + (size_t)n * H_;
    float acc = 0.f;
    for (int k = 0; k < H_; ++k) acc += xr[k] * (float)w[k];
    out[(size_t)b * H_ + n] = tanhf(acc + pb[n]);
  }
}

// ---------------------------------------------------------------------------
extern "C" void kernel_launch(void* const* d_in, const int* in_sizes, int n_in,
                              void* d_out, int out_size, void* d_ws,
                              size_t ws_size, hipStream_t stream) {
  (void)in_sizes; (void)n_in; (void)out_size;
  const int* ids = (const int*)d_in[0];
  const int* am = (const int*)d_in[1];
  const int* tt = (const int*)d_in[2];
  const float* we = (const float*)d_in[3];
  const float* se = (const float*)d_in[4];
  const float* pe = (const float*)d_in[5];
  const float* te = (const float*)d_in[6];
  const float* eg = (const float*)d_in[7];
  const float* ebb = (const float*)d_in[8];
  const float* Wq = (const float*)d_in[9];
  const float* bq = (const float*)d_in[10];
  const float* Wk = (const float*)d_in[11];
  const float* bk = (const float*)d_in[12];
  const float* Wv = (const float*)d_in[13];
  const float* bv = (const float*)d_in[14];
  const float* Wo = (const float*)d_in[15];
  const float* bo = (const float*)d_in[16];
  const float* g1 = (const float*)d_in[17];
  const float* b1 = (const float*)d_in[18];
  const float* Wi = (const float*)d_in[19];
  const float* bi = (const float*)d_in[20];
  const float* Wf = (const float*)d_in[21];
  const float* bf_ = (const float*)d_in[22];
  const float* g2 = (const float*)d_in[23];
  const float* b2 = (const float*)d_in[24];
  const float* pw = (const float*)d_in[25];
  const float* pb = (const float*)d_in[26];

  const size_t WQKV = (size_t)L_ * QKVN * H_;
  const size_t WSQ = (size_t)L_ * H_ * H_;
  const size_t WSF = (size_t)L_ * H_ * F_;
  __bf16* wqkv = (__bf16*)d_ws;
  __bf16* wTo_ = wqkv + WQKV;
  __bf16* wTi_ = wTo_ + WSQ;
  __bf16* wTf_ = wTi_ + WSF;
  __bf16* wTp_ = wTf_ + WSF;
  __bf16* xb = wTp_ + (size_t)H_ * H_;
  __bf16* qkvb = xb + (size_t)NTOK * H_;
  __bf16* cb = qkvb + (size_t)NTOK * QKVN;
  __bf16* mid = cb + (size_t)NTOK * H_;
  __bf16* vtb = mid + (size_t)NTOK * F_;
  float* t0 = (float*)(vtb + (size_t)NTOK * H_);
  float* bqkv = t0 + (size_t)NTOK * H_;
  const size_t needed = (size_t)((char*)(bqkv + (size_t)L_ * QKVN) - (char*)d_ws);
  if (ws_size < needed) return;  // insufficient scratch: visible failure

  float* x = (float*)d_out;
  float* pooled = x + (size_t)NTOK * H_;

  const dim3 tb(32, 8);
  const size_t zq = (size_t)QKVN * H_;
  transpose_k<<<dim3(24, 24, 12), tb, 0, stream>>>(Wq, wqkv, H_, H_, zq);
  transpose_k<<<dim3(24, 24, 12), tb, 0, stream>>>(Wk, wqkv + (size_t)H_ * H_, H_, H_, zq);
  transpose_k<<<dim3(24, 24, 12), tb, 0, stream>>>(Wv, wqkv + 2 * (size_t)H_ * H_, H_, H_, zq);
  transpose_k<<<dim3(24, 24, 12), tb, 0, stream>>>(Wo, wTo_, H_, H_, (size_t)H_ * H_);
  transpose_k<<<dim3(96, 24, 12), tb, 0, stream>>>(Wi, wTi_, H_, F_, (size_t)H_ * F_);
  transpose_k<<<dim3(24, 96, 12), tb, 0, stream>>>(Wf, wTf_, F_, H_, (size_t)H_ * F_);
  transpose_k<<<dim3(24, 24, 1), tb, 0, stream>>>(pw, wTp_, H_, H_, (size_t)H_ * H_);
  concat_bias<<<(L_ * QKVN + 255) / 256, 256, 0, stream>>>(bq, bk, bv, bqkv);

  embed_kernel<<<NTOK, 256, 0, stream>>>(ids, tt, we, se, pe, te, eg, ebb, x, xb);

  for (int l = 0; l < L_; ++l) {
    // fused QKV: [8192,2304], BM=128 -> 576 blocks
    gemm8n<0, 1><<<(NTOK / 128) * (QKVN / 256), 512, 0, stream>>>(
        xb, wqkv + (size_t)l * QKVN * H_, bqkv + (size_t)l * QKVN,
        nullptr, qkvb, NTOK, QKVN, H_, QKVN / 256);

    // V -> V^T (L2-resident, coalesced): vtb[(b*NH+h)*64+d][512]
    vtrans_kernel<<<dim3(16, 2, B_ * NH_), tb, 0, stream>>>(qkvb, vtb);

    attn_kernel<<<dim3(NH_, B_, 4), 256, 0, stream>>>(qkvb, vtb, am, cb);

    // attn-out: 192 blocks
    gemm8n<0, 0><<<(NTOK / 128) * (H_ / 256), 512, 0, stream>>>(
        cb, wTo_ + (size_t)l * H_ * H_, bo + l * H_, t0, nullptr,
        NTOK, H_, H_, H_ / 256);
    addln_kernel<<<NTOK / 4, 256, 0, stream>>>(x, t0, g1 + l * H_, b1 + l * H_, xb);

    // FF1: 768 blocks
    gemm8n<1, 1><<<(NTOK / 128) * (F_ / 256), 512, 0, stream>>>(
        xb, wTi_ + (size_t)l * H_ * F_, bi + l * F_, nullptr, mid,
        NTOK, F_, H_, F_ / 256);
    // FF2: 192 blocks
    gemm8n<0, 0><<<(NTOK / 128) * (H_ / 256), 512, 0, stream>>>(
        mid, wTf_ + (size_t)l * F_ * H_, bf_ + l * H_, t0, nullptr,
        NTOK, H_, F_, H_ / 256);
    addln_kernel<<<NTOK / 4, 256, 0, stream>>>(x, t0, g2 + l * H_, b2 + l * H_, xb);
  }

  pool_kernel<<<B_, 256, 0, stream>>>(x, wTp_, pb, pooled);
}

// Round 6
// 3912.650 us; speedup vs baseline: 1.2788x; 1.0851x over previous
//
#include <hip/hip_runtime.h>
#include <hip/hip_bf16.h>
#include <math.h>

// ---------------------------------------------------------------------------
// KVPLM Star Encoder: 12 layers, H=768, NH=12, F=3072, B=16, S=512.
// Round 6: GEMM -> T3-minimal 2-phase 128x128, 64 KiB LDS = 2 blocks/CU
// (m230 structure, 682 TF refcheck'd). One vmcnt(0)+barrier per K-tile;
// cross-block overlap replaces intra-block phasing. Attn: force 4 waves/SIMD.
// ---------------------------------------------------------------------------

#define L_   12
#define H_   768
#define NH_  12
#define DH_  64
#define F_   3072
#define B_   16
#define S_   512
#define NTOK (B_ * S_)   // 8192
#define QKVN 2304

typedef __attribute__((ext_vector_type(8))) __bf16 bf16x8;
typedef __attribute__((ext_vector_type(4))) __bf16 bf16x4;
typedef __attribute__((ext_vector_type(4))) float  f32x4;

static __device__ __forceinline__ f32x4 mfma16(bf16x8 a, bf16x8 b, f32x4 c) {
  return __builtin_amdgcn_mfma_f32_16x16x32_bf16(a, b, c, 0, 0, 0);
}

static __device__ __forceinline__ void load_lds16(const void* g, void* l) {
  __builtin_amdgcn_global_load_lds(
      (const __attribute__((address_space(1))) void*)g,
      (__attribute__((address_space(3))) void*)l, 16, 0, 0);
}

// ---------------------------------------------------------------------------
// Weight transpose+convert: in fp32 [Z][R][C] -> out bf16 [Z (stride outZ)][C][R]
// ---------------------------------------------------------------------------
__global__ __launch_bounds__(256) void transpose_k(const float* __restrict__ in,
                                                   __bf16* __restrict__ out,
                                                   int R, int C, size_t outZ) {
  __shared__ float t[32][33];
  const int z = blockIdx.z;
  const float* inz = in + (size_t)z * R * C;
  __bf16* outz = out + (size_t)z * outZ;
  const int c0 = blockIdx.x * 32, r0 = blockIdx.y * 32;
  const int tx = threadIdx.x, ty = threadIdx.y;
#pragma unroll
  for (int i = 0; i < 32; i += 8)
    t[ty + i][tx] = inz[(size_t)(r0 + ty + i) * C + c0 + tx];
  __syncthreads();
#pragma unroll
  for (int i = 0; i < 32; i += 8)
    outz[(size_t)(c0 + ty + i) * R + r0 + tx] = (__bf16)t[tx][ty + i];
}

__global__ __launch_bounds__(256) void concat_bias(const float* __restrict__ bq,
                                                   const float* __restrict__ bk,
                                                   const float* __restrict__ bv,
                                                   float* __restrict__ o) {
  const int i = blockIdx.x * 256 + threadIdx.x;
  if (i >= L_ * QKVN) return;
  const int l = i / QKVN, j = i - l * QKVN;
  float v;
  if (j < H_) v = bq[l * H_ + j];
  else if (j < 2 * H_) v = bk[l * H_ + j - H_];
  else v = bv[l * H_ + j - 2 * H_];
  o[i] = v;
}

// ---------------------------------------------------------------------------
// V transpose (per layer): qkv [NTOK][2304] cols 1536+ -> vt [(b*NH+h)*64+d][512]
// ---------------------------------------------------------------------------
__global__ __launch_bounds__(256) void vtrans_kernel(const __bf16* __restrict__ qkv,
                                                     __bf16* __restrict__ vt) {
  __shared__ __bf16 t[32][36];
  const int bh = blockIdx.z;           // b*NH + h
  const int bb = bh / NH_, hh = bh - bb * NH_;
  const int s0 = blockIdx.x * 32, d0 = blockIdx.y * 32;
  const int tx = threadIdx.x, ty = threadIdx.y;
  const __bf16* src = qkv + (size_t)(bb * S_) * QKVN + 2 * H_ + hh * DH_;
#pragma unroll
  for (int i = 0; i < 32; i += 8)
    t[ty + i][tx] = src[(size_t)(s0 + ty + i) * QKVN + d0 + tx];
  __syncthreads();
  __bf16* dst = vt + ((size_t)bh * DH_) * S_;
#pragma unroll
  for (int i = 0; i < 32; i += 8)
    dst[(size_t)(d0 + ty + i) * S_ + s0 + tx] = t[tx][ty + i];
}

// ---------------------------------------------------------------------------
// T3-minimal 2-phase 128x128 GEMM. 4 waves (2x2), 64x64 per wave, BK=64.
// LDS 64 KiB dbuf -> 2 blocks/CU (the m230 682-TF structure): per K-tile,
// {stage(t+1) -> ds_read(t) -> lgkmcnt(0) -> setprio+32 MFMA -> vmcnt(0) ->
// barrier}. Cross-block wave overlap hides the drain. T2 st_16x32 swizzle
// with inverse-swizzled global source (rule #21). XCD-swizzled blockIdx.
// ---------------------------------------------------------------------------
template <int EPI, int OUTBF>
__global__ __launch_bounds__(256, 2) void gemm2(const __bf16* __restrict__ A,
                                                const __bf16* __restrict__ Bt,
                                                const float* __restrict__ bias,
                                                float* __restrict__ Cf,
                                                __bf16* __restrict__ Cb,
                                                int M, int N, int K, int Ntiles) {
  alignas(16) __shared__ __bf16 lds[32768];  // [buf2][A 8192 | B 8192]
  const int tid = threadIdx.x, wid = tid >> 6, lane = tid & 63;
  int bid = blockIdx.x;
  const int nwg = gridDim.x;
  if ((nwg & 7) == 0) bid = (bid & 7) * (nwg >> 3) + (bid >> 3);  // XCD swizzle
  const int bm = (bid / Ntiles) << 7, bn = (bid % Ntiles) << 7;
  const int nt = K >> 6;

  // staging source coords: linear LDS el E -> logical (r,c) via st_16x32
  // inverse swizzle; region layout [rg8][cg2][16][32].
  const __bf16* pA[4];
  const __bf16* pB[4];
#pragma unroll
  for (int j = 0; j < 4; ++j) {
    const int E = (j << 11) + tid * 8;
    const int Ep = E ^ (((E >> 8) & 1) << 4);
    const int r = ((Ep >> 10) << 4) | ((Ep >> 5) & 15);
    const int c = (((Ep >> 9) & 1) << 5) | (Ep & 31);
    pA[j] = A + (size_t)(bm + r) * K + c;
    pB[j] = Bt + (size_t)(bn + r) * K + c;
  }

  auto stage = [&](int t, int buf) {
    __bf16* base = &lds[(buf << 14) + (wid << 9)];
    const size_t off = (size_t)(t << 6);
#pragma unroll
    for (int j = 0; j < 4; ++j) load_lds16(pA[j] + off, base + (j << 11));
#pragma unroll
    for (int j = 0; j < 4; ++j) load_lds16(pB[j] + off, base + 8192 + (j << 11));
  };

  const int frow = lane & 15, fk = (lane >> 4) << 3;
  const int swzb = (frow * 32 + fk) ^ (((frow >> 3) & 1) << 4);
  const int mh = wid >> 1, nq = wid & 1;  // 2x2 waves, 64x64 each

  f32x4 acc[4][4] = {};

  stage(0, 0);
  asm volatile("s_waitcnt vmcnt(0)" ::: "memory");
  __builtin_amdgcn_s_barrier();

  for (int t = 0; t < nt; ++t) {
    const int buf = t & 1;
    if (t + 1 < nt) stage(t + 1, buf ^ 1);   // issue BEFORE ds_read+MFMA
    const __bf16* LA = &lds[(buf << 14) + (mh << 12)];
    const __bf16* LB = &lds[(buf << 14) + 8192 + (nq << 12)];
    bf16x8 a[4][2], b[4][2];
#pragma unroll
    for (int mi = 0; mi < 4; ++mi)
#pragma unroll
      for (int ks = 0; ks < 2; ++ks)
        a[mi][ks] = *(const bf16x8*)&LA[mi * 1024 + ks * 512 + swzb];
#pragma unroll
    for (int ni = 0; ni < 4; ++ni)
#pragma unroll
      for (int ks = 0; ks < 2; ++ks)
        b[ni][ks] = *(const bf16x8*)&LB[ni * 1024 + ks * 512 + swzb];
    asm volatile("s_waitcnt lgkmcnt(0)" ::: "memory");
    __builtin_amdgcn_s_setprio(1);
#pragma unroll
    for (int mi = 0; mi < 4; ++mi)
#pragma unroll
      for (int ni = 0; ni < 4; ++ni)
#pragma unroll
        for (int ks = 0; ks < 2; ++ks)
          acc[mi][ni] = mfma16(a[mi][ks], b[ni][ks], acc[mi][ni]);
    __builtin_amdgcn_s_setprio(0);
    asm volatile("s_waitcnt vmcnt(0)" ::: "memory");  // next tile staged
    __builtin_amdgcn_s_barrier();
  }

  // epilogue: C/D layout col=lane&15, row=(lane>>4)*4+r  [m89 verified]
  const int r0 = (lane >> 4) << 2, c0 = lane & 15;
  const int wrow = bm + (mh << 6), wcol = bn + (nq << 6);
#pragma unroll
  for (int ni = 0; ni < 4; ++ni) {
    const int col = wcol + (ni << 4) + c0;
    const float bv = bias[col];
#pragma unroll
    for (int mi = 0; mi < 4; ++mi) {
      const int row = wrow + (mi << 4) + r0;
#pragma unroll
      for (int r = 0; r < 4; ++r) {
        float v = acc[mi][ni][r] + bv;
        if (EPI == 1) v = 0.5f * v * (1.0f + erff(v * 0.70710678118654752f));
        if (OUTBF)
          Cb[(size_t)(row + r) * N + col] = (__bf16)v;
        else
          Cf[(size_t)(row + r) * N + col] = v;
      }
    }
  }
}

// ---------------------------------------------------------------------------
// Flash attention, staging-free (K rows + pre-transposed V^T from L2-resident
// global). LDS: mask + per-wave P tile (9 KB). Grid (NH, B, 4) = 768 blocks.
// launch_bounds(256,4): force VGPR <=128 -> 4 waves/SIMD (latency-chain-bound).
// ---------------------------------------------------------------------------
__global__ __launch_bounds__(256, 4) void attn_kernel(const __bf16* __restrict__ qkv,
                                                      const __bf16* __restrict__ vt,
                                                      const int* __restrict__ amask,
                                                      __bf16* __restrict__ ctx) {
  __shared__ float extm[S_];
  __shared__ __bf16 Pl[4][16][56];     // per-wave P tile (pad 32->56)
  const int h = blockIdx.x, b = blockIdx.y, z = blockIdx.z;
  const int tid = threadIdx.x, wid = tid >> 6, lane = tid & 63;
  const size_t rowb = (size_t)b * S_ * QKVN + (size_t)h * DH_;
  const __bf16* vbase = vt + ((size_t)(b * NH_ + h) * DH_) * S_;

  for (int i = tid; i < S_; i += 256)
    extm[i] = (1.0f - (float)amask[b * S_ + i]) * -10000.0f;
  __syncthreads();

  const int c0 = lane & 15, g4 = lane >> 4;
  for (int qt = z * 4 + wid; qt < S_ / 16; qt += 16) {
    const __bf16* qrow = qkv + rowb + (size_t)(qt * 16 + c0) * QKVN + (g4 << 3);
    const bf16x8 qf0 = *(const bf16x8*)qrow;
    const bf16x8 qf1 = *(const bf16x8*)(qrow + 32);
    f32x4 oacc[4] = {};
    float mrow[4] = {-1e30f, -1e30f, -1e30f, -1e30f};
    float lsum[4] = {0.f, 0.f, 0.f, 0.f};

    for (int kt = 0; kt < 16; ++kt) {
      f32x4 sc[2];
#pragma unroll
      for (int f = 0; f < 2; ++f) {
        const int key = kt * 32 + f * 16 + c0;
        const __bf16* krow = qkv + rowb + (size_t)key * QKVN + H_ + (g4 << 3);
        const bf16x8 kf0 = *(const bf16x8*)krow;
        const bf16x8 kf1 = *(const bf16x8*)(krow + 32);
        f32x4 z2 = {};
        z2 = mfma16(qf0, kf0, z2);
        z2 = mfma16(qf1, kf1, z2);
        const float e = extm[key];
#pragma unroll
        for (int r = 0; r < 4; ++r) sc[f][r] = z2[r] * 0.125f + e;
      }
      float al[4];
#pragma unroll
      for (int r = 0; r < 4; ++r) {
        float mx = fmaxf(sc[0][r], sc[1][r]);
        mx = fmaxf(mx, __shfl_xor(mx, 1, 64));
        mx = fmaxf(mx, __shfl_xor(mx, 2, 64));
        mx = fmaxf(mx, __shfl_xor(mx, 4, 64));
        mx = fmaxf(mx, __shfl_xor(mx, 8, 64));
        const float mn = fmaxf(mrow[r], mx);
        al[r] = __expf(mrow[r] - mn);
        mrow[r] = mn;
        const float p0 = __expf(sc[0][r] - mn);
        const float p1 = __expf(sc[1][r] - mn);
        sc[0][r] = p0; sc[1][r] = p1;
        float rs = p0 + p1;
        rs += __shfl_xor(rs, 1, 64);
        rs += __shfl_xor(rs, 2, 64);
        rs += __shfl_xor(rs, 4, 64);
        rs += __shfl_xor(rs, 8, 64);
        lsum[r] = lsum[r] * al[r] + rs;
      }
#pragma unroll
      for (int f = 0; f < 2; ++f)
#pragma unroll
        for (int r = 0; r < 4; ++r)
          Pl[wid][g4 * 4 + r][f * 16 + c0] = (__bf16)sc[f][r];
#pragma unroll
      for (int dt = 0; dt < 4; ++dt)
#pragma unroll
        for (int r = 0; r < 4; ++r) oacc[dt][r] *= al[r];
      const bf16x8 pa = *(const bf16x8*)&Pl[wid][c0][g4 << 3];
#pragma unroll
      for (int dt = 0; dt < 4; ++dt) {
        const bf16x8 vf = *(const bf16x8*)&vbase[(size_t)(dt * 16 + c0) * S_ +
                                                kt * 32 + (g4 << 3)];
        oacc[dt] = mfma16(pa, vf, oacc[dt]);
      }
    }
    float inv[4];
#pragma unroll
    for (int r = 0; r < 4; ++r) inv[r] = 1.0f / lsum[r];
#pragma unroll
    for (int dt = 0; dt < 4; ++dt)
#pragma unroll
      for (int r = 0; r < 4; ++r)
        ctx[(size_t)b * S_ * H_ + (size_t)h * DH_ +
            (size_t)(qt * 16 + g4 * 4 + r) * H_ + dt * 16 + c0] =
            (__bf16)(oacc[dt][r] * inv[r]);
  }
}

// ---------------------------------------------------------------------------
// Residual add + LayerNorm, ONE WAVE PER TOKEN (no block barrier).
// ---------------------------------------------------------------------------
__global__ __launch_bounds__(256) void addln_kernel(float* __restrict__ x,
                                                    const float* __restrict__ t,
                                                    const float* __restrict__ g,
                                                    const float* __restrict__ bb,
                                                    __bf16* __restrict__ xb) {
  const int tok = blockIdx.x * 4 + (threadIdx.x >> 6);
  const int lane = threadIdx.x & 63;
  float* xr = x + (size_t)tok * H_;
  const float* tr = t + (size_t)tok * H_;
  f32x4 v[3];
  float s = 0.f, s2 = 0.f;
#pragma unroll
  for (int i = 0; i < 3; ++i) {
    const int off = lane * 4 + i * 256;
    f32x4 a = *(const f32x4*)&xr[off];
    f32x4 b = *(const f32x4*)&tr[off];
    v[i] = a + b;
#pragma unroll
    for (int r = 0; r < 4; ++r) { s += v[i][r]; s2 += v[i][r] * v[i][r]; }
  }
#pragma unroll
  for (int o = 32; o > 0; o >>= 1) {
    s += __shfl_xor(s, o, 64);
    s2 += __shfl_xor(s2, o, 64);
  }
  const float mean = s * (1.0f / 768.0f);
  const float var = s2 * (1.0f / 768.0f) - mean * mean;
  const float rstd = rsqrtf(var + 1e-12f);
  __bf16* xbr = xb + (size_t)tok * H_;
#pragma unroll
  for (int i = 0; i < 3; ++i) {
    const int off = lane * 4 + i * 256;
    f32x4 gv = *(const f32x4*)&g[off];
    f32x4 bv = *(const f32x4*)&bb[off];
    f32x4 y;
    bf16x4 yb;
#pragma unroll
    for (int r = 0; r < 4; ++r) {
      y[r] = (v[i][r] - mean) * rstd * gv[r] + bv[r];
      yb[r] = (__bf16)y[r];
    }
    *(f32x4*)&xr[off] = y;
    *(bf16x4*)&xbr[off] = yb;
  }
}

// ---------------------------------------------------------------------------
// Embedding (word/star select + pos + type) + LN.
// ---------------------------------------------------------------------------
__global__ __launch_bounds__(256) void embed_kernel(
    const int* __restrict__ ids, const int* __restrict__ tt,
    const float* __restrict__ we, const float* __restrict__ se,
    const float* __restrict__ pe, const float* __restrict__ te,
    const float* __restrict__ g, const float* __restrict__ bb,
    float* __restrict__ x, __bf16* __restrict__ xb) {
  const int tok = blockIdx.x, tid = threadIdx.x;
  const int sp = tok & (S_ - 1);
  const int id = ids[tok];
  const float* e = (id >= 30700) ? se + (size_t)(id - 30700) * H_
                                 : we + (size_t)id * H_;
  const float* pr = pe + (size_t)sp * H_;
  const float* ty = te + (size_t)tt[tok] * H_;
  float v0 = e[tid] + pr[tid] + ty[tid];
  float v1 = e[tid + 256] + pr[tid + 256] + ty[tid + 256];
  float v2 = e[tid + 512] + pr[tid + 512] + ty[tid + 512];
  float s = v0 + v1 + v2;
  float s2 = v0 * v0 + v1 * v1 + v2 * v2;
  __shared__ float red1[4], red2[4];
#pragma unroll
  for (int o = 32; o > 0; o >>= 1) {
    s += __shfl_xor(s, o, 64);
    s2 += __shfl_xor(s2, o, 64);
  }
  if ((tid & 63) == 0) { red1[tid >> 6] = s; red2[tid >> 6] = s2; }
  __syncthreads();
  s = red1[0] + red1[1] + red1[2] + red1[3];
  s2 = red2[0] + red2[1] + red2[2] + red2[3];
  const float mean = s * (1.0f / 768.0f);
  const float var = s2 * (1.0f / 768.0f) - mean * mean;
  const float rstd = rsqrtf(var + 1e-12f);
  float* xr = x + (size_t)tok * H_;
  __bf16* xbr = xb + (size_t)tok * H_;
  const float y0 = (v0 - mean) * rstd * g[tid] + bb[tid];
  const float y1 = (v1 - mean) * rstd * g[tid + 256] + bb[tid + 256];
  const float y2 = (v2 - mean) * rstd * g[tid + 512] + bb[tid + 512];
  xr[tid] = y0; xr[tid + 256] = y1; xr[tid + 512] = y2;
  xbr[tid] = (__bf16)y0; xbr[tid + 256] = (__bf16)y1; xbr[tid + 512] = (__bf16)y2;
}

// ---------------------------------------------------------------------------
// Pooler: pooled[b] = tanh(x[b,0,:] @ poolW + pool_b).
// ---------------------------------------------------------------------------
__global__ __launch_bounds__(256) void pool_kernel(const float* __restrict__ x,
                                                   const __bf16* __restrict__ wT,
                                                   const float* __restrict__ pb,
                                                   float* __restrict__ out) {
  const int b = blockIdx.x, tid = threadIdx.x;
  __shared__ float xr[H_];
  for (int i = tid; i < H_; i += 256) xr[i] = x[(size_t)b * S_ * H_ + i];
  __syncthreads();
  for (int n = tid; n < H_; n += 256) {
    const __bf16* w = wT + (size_t)n * H_;
    float acc = 0.f;
    for (int k = 0; k < H_; ++k) acc += xr[k] * (float)w[k];
    out[(size_t)b * H_ + n] = tanhf(acc + pb[n]);
  }
}

// ---------------------------------------------------------------------------
extern "C" void kernel_launch(void* const* d_in, const int* in_sizes, int n_in,
                              void* d_out, int out_size, void* d_ws,
                              size_t ws_size, hipStream_t stream) {
  (void)in_sizes; (void)n_in; (void)out_size;
  const int* ids = (const int*)d_in[0];
  const int* am = (const int*)d_in[1];
  const int* tt = (const int*)d_in[2];
  const float* we = (const float*)d_in[3];
  const float* se = (const float*)d_in[4];
  const float* pe = (const float*)d_in[5];
  const float* te = (const float*)d_in[6];
  const float* eg = (const float*)d_in[7];
  const float* ebb = (const float*)d_in[8];
  const float* Wq = (const float*)d_in[9];
  const float* bq = (const float*)d_in[10];
  const float* Wk = (const float*)d_in[11];
  const float* bk = (const float*)d_in[12];
  const float* Wv = (const float*)d_in[13];
  const float* bv = (const float*)d_in[14];
  const float* Wo = (const float*)d_in[15];
  const float* bo = (const float*)d_in[16];
  const float* g1 = (const float*)d_in[17];
  const float* b1 = (const float*)d_in[18];
  const float* Wi = (const float*)d_in[19];
  const float* bi = (const float*)d_in[20];
  const float* Wf = (const float*)d_in[21];
  const float* bf_ = (const float*)d_in[22];
  const float* g2 = (const float*)d_in[23];
  const float* b2 = (const float*)d_in[24];
  const float* pw = (const float*)d_in[25];
  const float* pb = (const float*)d_in[26];

  const size_t WQKV = (size_t)L_ * QKVN * H_;
  const size_t WSQ = (size_t)L_ * H_ * H_;
  const size_t WSF = (size_t)L_ * H_ * F_;
  __bf16* wqkv = (__bf16*)d_ws;
  __bf16* wTo_ = wqkv + WQKV;
  __bf16* wTi_ = wTo_ + WSQ;
  __bf16* wTf_ = wTi_ + WSF;
  __bf16* wTp_ = wTf_ + WSF;
  __bf16* xb = wTp_ + (size_t)H_ * H_;
  __bf16* qkvb = xb + (size_t)NTOK * H_;
  __bf16* cb = qkvb + (size_t)NTOK * QKVN;
  __bf16* mid = cb + (size_t)NTOK * H_;
  __bf16* vtb = mid + (size_t)NTOK * F_;
  float* t0 = (float*)(vtb + (size_t)NTOK * H_);
  float* bqkv = t0 + (size_t)NTOK * H_;
  const size_t needed = (size_t)((char*)(bqkv + (size_t)L_ * QKVN) - (char*)d_ws);
  if (ws_size < needed) return;  // insufficient scratch: visible failure

  float* x = (float*)d_out;
  float* pooled = x + (size_t)NTOK * H_;

  const dim3 tb(32, 8);
  const size_t zq = (size_t)QKVN * H_;
  transpose_k<<<dim3(24, 24, 12), tb, 0, stream>>>(Wq, wqkv, H_, H_, zq);
  transpose_k<<<dim3(24, 24, 12), tb, 0, stream>>>(Wk, wqkv + (size_t)H_ * H_, H_, H_, zq);
  transpose_k<<<dim3(24, 24, 12), tb, 0, stream>>>(Wv, wqkv + 2 * (size_t)H_ * H_, H_, H_, zq);
  transpose_k<<<dim3(24, 24, 12), tb, 0, stream>>>(Wo, wTo_, H_, H_, (size_t)H_ * H_);
  transpose_k<<<dim3(96, 24, 12), tb, 0, stream>>>(Wi, wTi_, H_, F_, (size_t)H_ * F_);
  transpose_k<<<dim3(24, 96, 12), tb, 0, stream>>>(Wf, wTf_, F_, H_, (size_t)H_ * F_);
  transpose_k<<<dim3(24, 24, 1), tb, 0, stream>>>(pw, wTp_, H_, H_, (size_t)H_ * H_);
  concat_bias<<<(L_ * QKVN + 255) / 256, 256, 0, stream>>>(bq, bk, bv, bqkv);

  embed_kernel<<<NTOK, 256, 0, stream>>>(ids, tt, we, se, pe, te, eg, ebb, x, xb);

  for (int l = 0; l < L_; ++l) {
    // fused QKV: [8192,2304] -> 64x18 = 1152 blocks
    gemm2<0, 1><<<(NTOK / 128) * (QKVN / 128), 256, 0, stream>>>(
        xb, wqkv + (size_t)l * QKVN * H_, bqkv + (size_t)l * QKVN,
        nullptr, qkvb, NTOK, QKVN, H_, QKVN / 128);

    vtrans_kernel<<<dim3(16, 2, B_ * NH_), tb, 0, stream>>>(qkvb, vtb);

    attn_kernel<<<dim3(NH_, B_, 4), 256, 0, stream>>>(qkvb, vtb, am, cb);

    // attn-out: 64x6 = 384 blocks
    gemm2<0, 0><<<(NTOK / 128) * (H_ / 128), 256, 0, stream>>>(
        cb, wTo_ + (size_t)l * H_ * H_, bo + l * H_, t0, nullptr,
        NTOK, H_, H_, H_ / 128);
    addln_kernel<<<NTOK / 4, 256, 0, stream>>>(x, t0, g1 + l * H_, b1 + l * H_, xb);

    // FF1: 64x24 = 1536 blocks
    gemm2<1, 1><<<(NTOK / 128) * (F_ / 128), 256, 0, stream>>>(
        xb, wTi_ + (size_t)l * H_ * F_, bi + l * F_, nullptr, mid,
        NTOK, F_, H_, F_ / 128);
    // FF2: 64x6 = 384 blocks
    gemm2<0, 0><<<(NTOK / 128) * (H_ / 128), 256, 0, stream>>>(
        mid, wTf_ + (size_t)l * F_ * H_, bf_ + l * H_, t0, nullptr,
        NTOK, H_, F_, H_ / 128);
    addln_kernel<<<NTOK / 4, 256, 0, stream>>>(x, t0, g2 + l * H_, b2 + l * H_, xb);
  }

  pool_kernel<<<B_, 256, 0, stream>>>(x, wTp_, pb, pooled);
}